// Round 1
// baseline (864.332 us; speedup 1.0000x reference)
//
#include <hip/hip_runtime.h>

// Problem constants (match reference)
constexpr int U_N = 50000;
constexpr int V_N = 50000;
constexpr int E_N = 800000;
// dims: F=64, G=64, H=16; g: 144->128->64; f: 128->128->64

__device__ __forceinline__ float relu(float x) { return fmaxf(x, 0.f); }

// ---------------------------------------------------------------------------
// proj: P[N][128] = X[N][64] @ W[64][128]   (no bias)
// block = 256 threads, 64 rows per block. W and X tile staged in LDS.
// ---------------------------------------------------------------------------
__global__ __launch_bounds__(256) void proj_kernel(const float* __restrict__ X,
                                                   const float* __restrict__ W,
                                                   float* __restrict__ P, int N)
{
    __shared__ float sW[64 * 128];  // 32 KB
    __shared__ float sX[64 * 64];   // 16 KB
    const int tid = threadIdx.x;
    const int row0 = blockIdx.x * 64;

    for (int i = tid * 4; i < 64 * 128; i += 1024)
        *(float4*)&sW[i] = *(const float4*)&W[i];
    for (int i = tid * 4; i < 64 * 64; i += 1024) {
        int r = i >> 6, c = i & 63;
        int gr = row0 + r;
        float4 val = (gr < N) ? *(const float4*)&X[(size_t)gr * 64 + c]
                              : make_float4(0.f, 0.f, 0.f, 0.f);
        *(float4*)&sX[i] = val;
    }
    __syncthreads();

    const int cg = tid & 31, rg = tid >> 5;
    const int c0 = cg * 4, r0 = rg * 8;
    float acc[8][4];
#pragma unroll
    for (int i = 0; i < 8; ++i)
#pragma unroll
        for (int j = 0; j < 4; ++j) acc[i][j] = 0.f;

#pragma unroll 4
    for (int k = 0; k < 64; ++k) {
        float4 w = *(const float4*)&sW[k * 128 + c0];
#pragma unroll
        for (int i = 0; i < 8; ++i) {
            float x = sX[(r0 + i) * 64 + k];
            acc[i][0] += x * w.x; acc[i][1] += x * w.y;
            acc[i][2] += x * w.z; acc[i][3] += x * w.w;
        }
    }
#pragma unroll
    for (int i = 0; i < 8; ++i) {
        int gr = row0 + r0 + i;
        if (gr < N) {
            float4 o = make_float4(acc[i][0], acc[i][1], acc[i][2], acc[i][3]);
            *(float4*)&P[(size_t)gr * 128 + c0] = o;
        }
    }
}

// ---------------------------------------------------------------------------
// edge kernel: per 64-edge tile
//   h1 = relu(Up[iu] + Vp[iv] + ev @ We + b1)            (64 x 128)
//   h2 = relu(h1 @ W2 + b2)                              (64 x 64)
//   atomicAdd agg[iu] += h2
// ---------------------------------------------------------------------------
__global__ __launch_bounds__(256, 2) void edge_kernel(
    const float* __restrict__ Up, const float* __restrict__ Vp,
    const float* __restrict__ ev, const int* __restrict__ idx_v,
    const int* __restrict__ idx_u,
    const float* __restrict__ gw1e,  // 16 x 128 (rows 128..143 of g_w1)
    const float* __restrict__ gb1,
    const float* __restrict__ gw2,   // 128 x 64
    const float* __restrict__ gb2,
    float* __restrict__ agg, int E)
{
    __shared__ float sW2[128 * 64];   // 32 KB
    __shared__ float sWe[16 * 128];   // 8 KB
    __shared__ float sEv[64 * 16];    // 4 KB
    __shared__ float sH1[64 * 132];   // 33 KB (stride 132: 2-way LDS alias only)
    __shared__ float sB1[128];
    __shared__ int   sIu[64];
    __shared__ int   sIv[64];

    const int tid = threadIdx.x;
    const int e0 = blockIdx.x * 64;

    for (int i = tid * 4; i < 128 * 64; i += 1024)
        *(float4*)&sW2[i] = *(const float4*)&gw2[i];
    for (int i = tid * 4; i < 16 * 128; i += 1024)
        *(float4*)&sWe[i] = *(const float4*)&gw1e[i];
    if (tid < 32) *(float4*)&sB1[tid * 4] = *(const float4*)&gb1[tid * 4];
    if (tid < 64) {
        int e = e0 + tid;
        sIu[tid] = (e < E) ? idx_u[e] : -1;
        sIv[tid] = (e < E) ? idx_v[e] : 0;
    }
    {
        int i = tid * 4;  // exactly 1024 floats with 256 threads
        int e = i >> 4, k = i & 15;
        int ge = e0 + e;
        float4 val = (ge < E) ? *(const float4*)&ev[(size_t)ge * 16 + k]
                              : make_float4(0.f, 0.f, 0.f, 0.f);
        *(float4*)&sEv[i] = val;
    }
    __syncthreads();

    // ---- layer 1: 64 edges x 128 cols, thread = 8 edges x 4 cols ----
    {
        const int cg = tid & 31, rg = tid >> 5;
        const int c0 = cg * 4;
        const float4 b1 = *(const float4*)&sB1[c0];
        float acc[8][4];
#pragma unroll
        for (int i = 0; i < 8; ++i) {
            int e = rg * 8 + i;
            int iu = sIu[e]; if (iu < 0) iu = 0;
            int iv = sIv[e];
            float4 a = *(const float4*)&Up[(size_t)iu * 128 + c0];
            float4 b = *(const float4*)&Vp[(size_t)iv * 128 + c0];
            acc[i][0] = b1.x + a.x + b.x;
            acc[i][1] = b1.y + a.y + b.y;
            acc[i][2] = b1.z + a.z + b.z;
            acc[i][3] = b1.w + a.w + b.w;
        }
#pragma unroll
        for (int k = 0; k < 16; ++k) {
            float4 w = *(const float4*)&sWe[k * 128 + c0];
#pragma unroll
            for (int i = 0; i < 8; ++i) {
                float x = sEv[(rg * 8 + i) * 16 + k];
                acc[i][0] += x * w.x; acc[i][1] += x * w.y;
                acc[i][2] += x * w.z; acc[i][3] += x * w.w;
            }
        }
#pragma unroll
        for (int i = 0; i < 8; ++i) {
            int e = rg * 8 + i;
            float4 h = make_float4(relu(acc[i][0]), relu(acc[i][1]),
                                   relu(acc[i][2]), relu(acc[i][3]));
            *(float4*)&sH1[e * 132 + c0] = h;
        }
    }
    __syncthreads();

    // ---- layer 2 + scatter: 64 edges x 64 cols, thread = 4 edges x 4 cols ----
    {
        const int cg = tid & 15, rg = tid >> 4;
        const int c0 = cg * 4;
        const float4 b2 = *(const float4*)&gb2[c0];
        float acc[4][4];
#pragma unroll
        for (int i = 0; i < 4; ++i) {
            acc[i][0] = b2.x; acc[i][1] = b2.y; acc[i][2] = b2.z; acc[i][3] = b2.w;
        }
#pragma unroll 4
        for (int k = 0; k < 128; ++k) {
            float4 w = *(const float4*)&sW2[k * 64 + c0];
#pragma unroll
            for (int i = 0; i < 4; ++i) {
                float h = sH1[(rg * 4 + i) * 132 + k];
                acc[i][0] += h * w.x; acc[i][1] += h * w.y;
                acc[i][2] += h * w.z; acc[i][3] += h * w.w;
            }
        }
#pragma unroll
        for (int i = 0; i < 4; ++i) {
            int e = rg * 4 + i;
            if (e0 + e < E) {
                int iu = sIu[e];
                float* dst = &agg[(size_t)iu * 64 + c0];
                atomicAdd(dst + 0, relu(acc[i][0]));
                atomicAdd(dst + 1, relu(acc[i][1]));
                atomicAdd(dst + 2, relu(acc[i][2]));
                atomicAdd(dst + 3, relu(acc[i][3]));
            }
        }
    }
}

// ---------------------------------------------------------------------------
// node kernel: out = relu(relu([u, agg] @ fw1 + fb1) @ fw2 + fb2)
// block = 256 threads, 64 rows per block; weights streamed from L2.
// ---------------------------------------------------------------------------
__global__ __launch_bounds__(256) void node_kernel(
    const float* __restrict__ u, const float* __restrict__ agg,
    const float* __restrict__ fw1, const float* __restrict__ fb1,
    const float* __restrict__ fw2, const float* __restrict__ fb2,
    float* __restrict__ out, int N)
{
    __shared__ float sX[64 * 128];  // 32 KB
    __shared__ float sY[64 * 132];  // 33 KB
    const int tid = threadIdx.x;
    const int row0 = blockIdx.x * 64;

    for (int i = tid * 4; i < 64 * 64; i += 1024) {
        int r = i >> 6, c = i & 63;
        int gr = row0 + r;
        float4 uu = (gr < N) ? *(const float4*)&u[(size_t)gr * 64 + c]
                             : make_float4(0.f, 0.f, 0.f, 0.f);
        float4 aa = (gr < N) ? *(const float4*)&agg[(size_t)gr * 64 + c]
                             : make_float4(0.f, 0.f, 0.f, 0.f);
        *(float4*)&sX[r * 128 + c] = uu;
        *(float4*)&sX[r * 128 + 64 + c] = aa;
    }
    __syncthreads();

    // layer 1: y = relu(x @ fw1 + fb1), thread = 8 rows x 4 cols
    {
        const int cg = tid & 31, rg = tid >> 5;
        const int c0 = cg * 4, r0 = rg * 8;
        const float4 b = *(const float4*)&fb1[c0];
        float acc[8][4];
#pragma unroll
        for (int i = 0; i < 8; ++i) {
            acc[i][0] = b.x; acc[i][1] = b.y; acc[i][2] = b.z; acc[i][3] = b.w;
        }
#pragma unroll 4
        for (int k = 0; k < 128; ++k) {
            float4 w = *(const float4*)&fw1[k * 128 + c0];
#pragma unroll
            for (int i = 0; i < 8; ++i) {
                float x = sX[(r0 + i) * 128 + k];
                acc[i][0] += x * w.x; acc[i][1] += x * w.y;
                acc[i][2] += x * w.z; acc[i][3] += x * w.w;
            }
        }
#pragma unroll
        for (int i = 0; i < 8; ++i) {
            float4 h = make_float4(relu(acc[i][0]), relu(acc[i][1]),
                                   relu(acc[i][2]), relu(acc[i][3]));
            *(float4*)&sY[(r0 + i) * 132 + c0] = h;
        }
    }
    __syncthreads();

    // layer 2: out = relu(y @ fw2 + fb2), thread = 4 rows x 4 cols
    {
        const int cg = tid & 15, rg = tid >> 4;
        const int c0 = cg * 4;
        const float4 b = *(const float4*)&fb2[c0];
        float acc[4][4];
#pragma unroll
        for (int i = 0; i < 4; ++i) {
            acc[i][0] = b.x; acc[i][1] = b.y; acc[i][2] = b.z; acc[i][3] = b.w;
        }
#pragma unroll 4
        for (int k = 0; k < 128; ++k) {
            float4 w = *(const float4*)&fw2[k * 64 + c0];
#pragma unroll
            for (int i = 0; i < 4; ++i) {
                float yv = sY[(rg * 4 + i) * 132 + k];
                acc[i][0] += yv * w.x; acc[i][1] += yv * w.y;
                acc[i][2] += yv * w.z; acc[i][3] += yv * w.w;
            }
        }
#pragma unroll
        for (int i = 0; i < 4; ++i) {
            int gr = row0 + rg * 4 + i;
            if (gr < N) {
                float4 o = make_float4(relu(acc[i][0]), relu(acc[i][1]),
                                       relu(acc[i][2]), relu(acc[i][3]));
                *(float4*)&out[(size_t)gr * 64 + c0] = o;
            }
        }
    }
}

// ---------------------------------------------------------------------------
extern "C" void kernel_launch(void* const* d_in, const int* in_sizes, int n_in,
                              void* d_out, int out_size, void* d_ws, size_t ws_size,
                              hipStream_t stream)
{
    const float* u   = (const float*)d_in[0];
    const float* v   = (const float*)d_in[1];
    const float* ev  = (const float*)d_in[2];
    const int*   eiv = (const int*)d_in[3];
    const int*   eiu = (const int*)d_in[4];
    const float* gw1 = (const float*)d_in[5];   // 144 x 128
    const float* gb1 = (const float*)d_in[6];   // 128
    const float* gw2 = (const float*)d_in[7];   // 128 x 64
    const float* gb2 = (const float*)d_in[8];   // 64
    const float* fw1 = (const float*)d_in[9];   // 128 x 128
    const float* fb1 = (const float*)d_in[10];  // 128
    const float* fw2 = (const float*)d_in[11];  // 128 x 64
    const float* fb2 = (const float*)d_in[12];  // 64
    float* out = (float*)d_out;

    // workspace layout
    float* Up  = (float*)d_ws;                       // 50000 x 128
    float* Vp  = Up + (size_t)U_N * 128;             // 50000 x 128
    float* agg = Vp + (size_t)V_N * 128;             // 50000 x 64

    hipMemsetAsync(agg, 0, (size_t)U_N * 64 * sizeof(float), stream);

    dim3 blk(256);
    proj_kernel<<<dim3((U_N + 63) / 64), blk, 0, stream>>>(u, gw1, Up, U_N);
    proj_kernel<<<dim3((V_N + 63) / 64), blk, 0, stream>>>(v, gw1 + 64 * 128, Vp, V_N);
    edge_kernel<<<dim3((E_N + 63) / 64), blk, 0, stream>>>(
        Up, Vp, ev, eiv, eiu, gw1 + 128 * 128, gb1, gw2, gb2, agg, E_N);
    node_kernel<<<dim3((U_N + 63) / 64), blk, 0, stream>>>(
        u, agg, fw1, fb1, fw2, fb2, out, U_N);
}

// Round 2
// 837.319 us; speedup vs baseline: 1.0323x; 1.0323x over previous
//
#include <hip/hip_runtime.h>

// Problem constants (match reference)
constexpr int U_N = 50000;
constexpr int V_N = 50000;
constexpr int E_N = 800000;   // == 64 * 12500, no tail in edge kernel
// dims: F=64, G=64, H=16; g: 144->128->64; f: 128->128->64

__device__ __forceinline__ float relu(float x) { return fmaxf(x, 0.f); }

// ---------------------------------------------------------------------------
// proj: P[N][128] = X[N][64] @ W[64][128]   (no bias)
// ---------------------------------------------------------------------------
__global__ __launch_bounds__(256) void proj_kernel(const float* __restrict__ X,
                                                   const float* __restrict__ W,
                                                   float* __restrict__ P, int N)
{
    __shared__ float sW[64 * 128];  // 32 KB
    __shared__ float sX[64 * 64];   // 16 KB
    const int tid = threadIdx.x;
    const int row0 = blockIdx.x * 64;

    for (int i = tid * 4; i < 64 * 128; i += 1024)
        *(float4*)&sW[i] = *(const float4*)&W[i];
    for (int i = tid * 4; i < 64 * 64; i += 1024) {
        int r = i >> 6, c = i & 63;
        int gr = row0 + r;
        float4 val = (gr < N) ? *(const float4*)&X[(size_t)gr * 64 + c]
                              : make_float4(0.f, 0.f, 0.f, 0.f);
        *(float4*)&sX[i] = val;
    }
    __syncthreads();

    const int cg = tid & 31, rg = tid >> 5;
    const int c0 = cg * 4, r0 = rg * 8;
    float acc[8][4];
#pragma unroll
    for (int i = 0; i < 8; ++i)
#pragma unroll
        for (int j = 0; j < 4; ++j) acc[i][j] = 0.f;

#pragma unroll 4
    for (int k = 0; k < 64; ++k) {
        float4 w = *(const float4*)&sW[k * 128 + c0];
#pragma unroll
        for (int i = 0; i < 8; ++i) {
            float x = sX[(r0 + i) * 64 + k];
            acc[i][0] += x * w.x; acc[i][1] += x * w.y;
            acc[i][2] += x * w.z; acc[i][3] += x * w.w;
        }
    }
#pragma unroll
    for (int i = 0; i < 8; ++i) {
        int gr = row0 + r0 + i;
        if (gr < N) {
            float4 o = make_float4(acc[i][0], acc[i][1], acc[i][2], acc[i][3]);
            *(float4*)&P[(size_t)gr * 128 + c0] = o;
        }
    }
}

// ---------------------------------------------------------------------------
// edge kernel: per 64-edge tile (E divisible by 64 -> no tail checks)
//   h1 = relu(Up[iu] + Vp[iv] + ev @ We + b1)            (64 x 128)
//   h2 = relu(h1 @ W2 + b2)                              (64 x 64)
//   atomicAdd agg[iu] += h2
// LDS: sEv 4K + sH1 33K + sB1 0.5K + sIu 0.25K ~= 38 KB -> 4 blocks/CU.
// We/W2 streamed from global (identical for all blocks; L1/L2-resident).
// ---------------------------------------------------------------------------
__global__ __launch_bounds__(256, 4) void edge_kernel(
    const float* __restrict__ Up, const float* __restrict__ Vp,
    const float* __restrict__ ev, const int* __restrict__ idx_v,
    const int* __restrict__ idx_u,
    const float* __restrict__ gw1e,  // 16 x 128 (rows 128..143 of g_w1)
    const float* __restrict__ gb1,
    const float* __restrict__ gw2,   // 128 x 64
    const float* __restrict__ gb2,
    float* __restrict__ agg)
{
    __shared__ float sEv[64 * 16];    // 4 KB
    __shared__ float sH1[64 * 132];   // 33 KB (stride 132 keeps float4 align, 2-way alias only)
    __shared__ float sB1[128];
    __shared__ int   sIu[64];

    const int tid = threadIdx.x;
    const int e0 = blockIdx.x * 64;

    // --- stage ev (coalesced), bias, iu for layer-2 ---
    if (tid < 32) *(float4*)&sB1[tid * 4] = *(const float4*)&gb1[tid * 4];
    if (tid < 64) sIu[tid] = idx_u[e0 + tid];
    {
        int i = tid * 4;  // exactly 1024 floats with 256 threads
        int e = i >> 4, k = i & 15;
        *(float4*)&sEv[i] = *(const float4*)&ev[(size_t)(e0 + e) * 16 + k];
    }

    // --- layer-1 mapping: thread = 8 edges x 4 cols ---
    const int cg = tid & 31, rg = tid >> 5;
    const int c0 = cg * 4;

    // Issue gathers BEFORE the barrier so they overlap staging; fold into acc
    // immediately to keep register lifetimes short.
    float acc[8][4];
#pragma unroll
    for (int i = 0; i < 8; ++i) {
        int e = e0 + rg * 8 + i;
        int iu = idx_u[e];
        int iv = idx_v[e];
        float4 a = *(const float4*)&Up[(size_t)iu * 128 + c0];
        float4 b = *(const float4*)&Vp[(size_t)iv * 128 + c0];
        acc[i][0] = a.x + b.x;
        acc[i][1] = a.y + b.y;
        acc[i][2] = a.z + b.z;
        acc[i][3] = a.w + b.w;
    }
    __syncthreads();

    // ev @ We (We streamed from global) + bias
    {
        const float4 b1 = *(const float4*)&sB1[c0];
#pragma unroll
        for (int i = 0; i < 8; ++i) {
            acc[i][0] += b1.x; acc[i][1] += b1.y;
            acc[i][2] += b1.z; acc[i][3] += b1.w;
        }
#pragma unroll
        for (int k = 0; k < 16; ++k) {
            float4 w = *(const float4*)&gw1e[k * 128 + c0];
#pragma unroll
            for (int i = 0; i < 8; ++i) {
                float x = sEv[(rg * 8 + i) * 16 + k];
                acc[i][0] += x * w.x; acc[i][1] += x * w.y;
                acc[i][2] += x * w.z; acc[i][3] += x * w.w;
            }
        }
#pragma unroll
        for (int i = 0; i < 8; ++i) {
            int e = rg * 8 + i;
            float4 h = make_float4(relu(acc[i][0]), relu(acc[i][1]),
                                   relu(acc[i][2]), relu(acc[i][3]));
            *(float4*)&sH1[e * 132 + c0] = h;
        }
    }
    __syncthreads();

    // ---- layer 2 + scatter: thread = 4 edges x 4 cols; W2 streamed ----
    {
        const int cg2 = tid & 15, rg2 = tid >> 4;
        const int c02 = cg2 * 4;
        const float4 b2 = *(const float4*)&gb2[c02];
        float acc2[4][4];
#pragma unroll
        for (int i = 0; i < 4; ++i) {
            acc2[i][0] = b2.x; acc2[i][1] = b2.y;
            acc2[i][2] = b2.z; acc2[i][3] = b2.w;
        }
#pragma unroll 4
        for (int k = 0; k < 128; ++k) {
            float4 w = *(const float4*)&gw2[k * 64 + c02];
#pragma unroll
            for (int i = 0; i < 4; ++i) {
                float h = sH1[(rg2 * 4 + i) * 132 + k];
                acc2[i][0] += h * w.x; acc2[i][1] += h * w.y;
                acc2[i][2] += h * w.z; acc2[i][3] += h * w.w;
            }
        }
#pragma unroll
        for (int i = 0; i < 4; ++i) {
            int e = rg2 * 4 + i;
            int iu = sIu[e];
            float* dst = &agg[(size_t)iu * 64 + c02];
            atomicAdd(dst + 0, relu(acc2[i][0]));
            atomicAdd(dst + 1, relu(acc2[i][1]));
            atomicAdd(dst + 2, relu(acc2[i][2]));
            atomicAdd(dst + 3, relu(acc2[i][3]));
        }
    }
}

// ---------------------------------------------------------------------------
// node kernel: out = relu(relu([u, agg] @ fw1 + fb1) @ fw2 + fb2)
// ---------------------------------------------------------------------------
__global__ __launch_bounds__(256) void node_kernel(
    const float* __restrict__ u, const float* __restrict__ agg,
    const float* __restrict__ fw1, const float* __restrict__ fb1,
    const float* __restrict__ fw2, const float* __restrict__ fb2,
    float* __restrict__ out, int N)
{
    __shared__ float sX[64 * 128];  // 32 KB
    __shared__ float sY[64 * 132];  // 33 KB
    const int tid = threadIdx.x;
    const int row0 = blockIdx.x * 64;

    for (int i = tid * 4; i < 64 * 64; i += 1024) {
        int r = i >> 6, c = i & 63;
        int gr = row0 + r;
        float4 uu = (gr < N) ? *(const float4*)&u[(size_t)gr * 64 + c]
                             : make_float4(0.f, 0.f, 0.f, 0.f);
        float4 aa = (gr < N) ? *(const float4*)&agg[(size_t)gr * 64 + c]
                             : make_float4(0.f, 0.f, 0.f, 0.f);
        *(float4*)&sX[r * 128 + c] = uu;
        *(float4*)&sX[r * 128 + 64 + c] = aa;
    }
    __syncthreads();

    // layer 1: y = relu(x @ fw1 + fb1), thread = 8 rows x 4 cols
    {
        const int cg = tid & 31, rg = tid >> 5;
        const int c0 = cg * 4, r0 = rg * 8;
        const float4 b = *(const float4*)&fb1[c0];
        float acc[8][4];
#pragma unroll
        for (int i = 0; i < 8; ++i) {
            acc[i][0] = b.x; acc[i][1] = b.y; acc[i][2] = b.z; acc[i][3] = b.w;
        }
#pragma unroll 4
        for (int k = 0; k < 128; ++k) {
            float4 w = *(const float4*)&fw1[k * 128 + c0];
#pragma unroll
            for (int i = 0; i < 8; ++i) {
                float x = sX[(r0 + i) * 128 + k];
                acc[i][0] += x * w.x; acc[i][1] += x * w.y;
                acc[i][2] += x * w.z; acc[i][3] += x * w.w;
            }
        }
#pragma unroll
        for (int i = 0; i < 8; ++i) {
            float4 h = make_float4(relu(acc[i][0]), relu(acc[i][1]),
                                   relu(acc[i][2]), relu(acc[i][3]));
            *(float4*)&sY[(r0 + i) * 132 + c0] = h;
        }
    }
    __syncthreads();

    // layer 2: out = relu(y @ fw2 + fb2), thread = 4 rows x 4 cols
    {
        const int cg = tid & 15, rg = tid >> 4;
        const int c0 = cg * 4;
        const float4 b = *(const float4*)&fb2[c0];
        float acc[4][4];
#pragma unroll
        for (int i = 0; i < 4; ++i) {
            acc[i][0] = b.x; acc[i][1] = b.y; acc[i][2] = b.z; acc[i][3] = b.w;
        }
#pragma unroll 4
        for (int k = 0; k < 128; ++k) {
            float4 w = *(const float4*)&fw2[k * 64 + c0];
#pragma unroll
            for (int i = 0; i < 4; ++i) {
                float yv = sY[(rg * 4 + i) * 132 + k];
                acc[i][0] += yv * w.x; acc[i][1] += yv * w.y;
                acc[i][2] += yv * w.z; acc[i][3] += yv * w.w;
            }
        }
#pragma unroll
        for (int i = 0; i < 4; ++i) {
            int gr = row0 + rg * 4 + i;
            if (gr < N) {
                float4 o = make_float4(relu(acc[i][0]), relu(acc[i][1]),
                                       relu(acc[i][2]), relu(acc[i][3]));
                *(float4*)&out[(size_t)gr * 64 + c0] = o;
            }
        }
    }
}

// ---------------------------------------------------------------------------
extern "C" void kernel_launch(void* const* d_in, const int* in_sizes, int n_in,
                              void* d_out, int out_size, void* d_ws, size_t ws_size,
                              hipStream_t stream)
{
    const float* u   = (const float*)d_in[0];
    const float* v   = (const float*)d_in[1];
    const float* ev  = (const float*)d_in[2];
    const int*   eiv = (const int*)d_in[3];
    const int*   eiu = (const int*)d_in[4];
    const float* gw1 = (const float*)d_in[5];   // 144 x 128
    const float* gb1 = (const float*)d_in[6];   // 128
    const float* gw2 = (const float*)d_in[7];   // 128 x 64
    const float* gb2 = (const float*)d_in[8];   // 64
    const float* fw1 = (const float*)d_in[9];   // 128 x 128
    const float* fb1 = (const float*)d_in[10];  // 128
    const float* fw2 = (const float*)d_in[11];  // 128 x 64
    const float* fb2 = (const float*)d_in[12];  // 64
    float* out = (float*)d_out;

    // workspace layout
    float* Up  = (float*)d_ws;                       // 50000 x 128
    float* Vp  = Up + (size_t)U_N * 128;             // 50000 x 128
    float* agg = Vp + (size_t)V_N * 128;             // 50000 x 64

    hipMemsetAsync(agg, 0, (size_t)U_N * 64 * sizeof(float), stream);

    dim3 blk(256);
    proj_kernel<<<dim3((U_N + 63) / 64), blk, 0, stream>>>(u, gw1, Up, U_N);
    proj_kernel<<<dim3((V_N + 63) / 64), blk, 0, stream>>>(v, gw1 + 64 * 128, Vp, V_N);
    edge_kernel<<<dim3(E_N / 64), blk, 0, stream>>>(
        Up, Vp, ev, eiv, eiu, gw1 + 128 * 128, gb1, gw2, gb2, agg);
    node_kernel<<<dim3((U_N + 63) / 64), blk, 0, stream>>>(
        u, agg, fw1, fb1, fw2, fb2, out, U_N);
}

// Round 3
// 552.480 us; speedup vs baseline: 1.5645x; 1.5156x over previous
//
#include <hip/hip_runtime.h>

// Problem constants (match reference)
constexpr int U_N = 50000;
constexpr int V_N = 50000;
constexpr int E_N = 800000;   // == 64 * 12500, no tail in edge kernel
// dims: F=64, G=64, H=16; g: 144->128->64; f: 128->128->64

__device__ __forceinline__ float relu(float x) { return fmaxf(x, 0.f); }

// ---------------------------------------------------------------------------
// Counting sort of edges by idx_u: histogram -> exclusive scan -> permutation
// ---------------------------------------------------------------------------
__global__ __launch_bounds__(256) void hist_kernel(const int* __restrict__ idx_u,
                                                   int* __restrict__ counts)
{
    int e = blockIdx.x * 256 + threadIdx.x;
    if (e < E_N) atomicAdd(&counts[idx_u[e]], 1);
}

// single block, 1024 threads: exclusive scan of counts[0..U_N) -> cursor
__global__ __launch_bounds__(1024) void scan_kernel(const int* __restrict__ counts,
                                                    int* __restrict__ cursor)
{
    __shared__ int sPart[1024];
    const int tid = threadIdx.x;
    constexpr int CH = 49;          // 1024*49 = 50176 >= 50000
    const int base = tid * CH;

    int sum = 0;
#pragma unroll
    for (int k = 0; k < CH; ++k) {
        int i = base + k;
        if (i < U_N) sum += counts[i];
    }
    sPart[tid] = sum;
    __syncthreads();
    // inclusive Hillis-Steele scan
    for (int off = 1; off < 1024; off <<= 1) {
        int v = (tid >= off) ? sPart[tid - off] : 0;
        __syncthreads();
        sPart[tid] += v;
        __syncthreads();
    }
    int run = sPart[tid] - sum;     // exclusive prefix for this chunk
    for (int k = 0; k < CH; ++k) {
        int i = base + k;
        if (i < U_N) { cursor[i] = run; run += counts[i]; }
    }
}

__global__ __launch_bounds__(256) void permute_kernel(const int* __restrict__ idx_u,
                                                      int* __restrict__ cursor,
                                                      int* __restrict__ perm)
{
    int e = blockIdx.x * 256 + threadIdx.x;
    if (e < E_N) {
        int pos = atomicAdd(&cursor[idx_u[e]], 1);
        perm[pos] = e;
    }
}

// ---------------------------------------------------------------------------
// proj: P[N][128] = X[N][64] @ W[64][128]   (no bias)
// ---------------------------------------------------------------------------
__global__ __launch_bounds__(256) void proj_kernel(const float* __restrict__ X,
                                                   const float* __restrict__ W,
                                                   float* __restrict__ P, int N)
{
    __shared__ float sW[64 * 128];  // 32 KB
    __shared__ float sX[64 * 64];   // 16 KB
    const int tid = threadIdx.x;
    const int row0 = blockIdx.x * 64;

    for (int i = tid * 4; i < 64 * 128; i += 1024)
        *(float4*)&sW[i] = *(const float4*)&W[i];
    for (int i = tid * 4; i < 64 * 64; i += 1024) {
        int r = i >> 6, c = i & 63;
        int gr = row0 + r;
        float4 val = (gr < N) ? *(const float4*)&X[(size_t)gr * 64 + c]
                              : make_float4(0.f, 0.f, 0.f, 0.f);
        *(float4*)&sX[i] = val;
    }
    __syncthreads();

    const int cg = tid & 31, rg = tid >> 5;
    const int c0 = cg * 4, r0 = rg * 8;
    float acc[8][4];
#pragma unroll
    for (int i = 0; i < 8; ++i)
#pragma unroll
        for (int j = 0; j < 4; ++j) acc[i][j] = 0.f;

#pragma unroll 4
    for (int k = 0; k < 64; ++k) {
        float4 w = *(const float4*)&sW[k * 128 + c0];
#pragma unroll
        for (int i = 0; i < 8; ++i) {
            float x = sX[(r0 + i) * 64 + k];
            acc[i][0] += x * w.x; acc[i][1] += x * w.y;
            acc[i][2] += x * w.z; acc[i][3] += x * w.w;
        }
    }
#pragma unroll
    for (int i = 0; i < 8; ++i) {
        int gr = row0 + r0 + i;
        if (gr < N) {
            float4 o = make_float4(acc[i][0], acc[i][1], acc[i][2], acc[i][3]);
            *(float4*)&P[(size_t)gr * 128 + c0] = o;
        }
    }
}

// ---------------------------------------------------------------------------
// edge kernel over SORTED edges: per 64-edge tile
//   h1 = relu(Up[iu] + Vp[iv] + ev @ We + b1)            (64 x 128)
//   h2 = relu(h1 @ W2 + b2)                              (64 x 64)
//   segmented sum of h2 over runs of equal iu -> few atomics into agg
// LDS ~= 39 KB -> 4 blocks/CU.
// ---------------------------------------------------------------------------
__global__ __launch_bounds__(256, 4) void edge_kernel(
    const float* __restrict__ Up, const float* __restrict__ Vp,
    const float* __restrict__ ev, const int* __restrict__ idx_v,
    const int* __restrict__ idx_u, const int* __restrict__ perm,
    const float* __restrict__ gw1e,  // 16 x 128 (rows 128..143 of g_w1)
    const float* __restrict__ gb1,
    const float* __restrict__ gw2,   // 128 x 64
    const float* __restrict__ gb2,
    float* __restrict__ agg)
{
    __shared__ float sH1[64 * 132];   // 33 KB; reused as sH2[64][68] later
    __shared__ float sEv[64 * 16];    // 4 KB
    __shared__ float sB1[128];
    __shared__ int   sIu[64];
    __shared__ int   sIv[64];
    __shared__ int   sPerm[64];

    const int tid = threadIdx.x;
    const int e0 = blockIdx.x * 64;

    if (tid < 64) {
        int p = perm[e0 + tid];
        sPerm[tid] = p;
        sIu[tid] = idx_u[p];
        sIv[tid] = idx_v[p];
    } else if (tid < 96) {
        int j = (tid - 64) * 4;
        *(float4*)&sB1[j] = *(const float4*)&gb1[j];
    }
    __syncthreads();

    // --- stage ev rows (gathered via perm; 64B rows, LLC-resident) ---
    {
        int i = tid * 4;  // exactly 1024 floats with 256 threads
        int e = i >> 4, k = i & 15;
        *(float4*)&sEv[i] = *(const float4*)&ev[(size_t)sPerm[e] * 16 + k];
    }

    // --- layer-1 mapping: thread = 8 edges x 4 cols ---
    const int cg = tid & 31, rg = tid >> 5;
    const int c0 = cg * 4;

    // Gather Up/Vp rows (sorted: Up rows repeat -> L1 hits). Issued before the
    // barrier so they overlap the sEv staging.
    float acc[8][4];
#pragma unroll
    for (int i = 0; i < 8; ++i) {
        int e = rg * 8 + i;
        int iu = sIu[e];
        int iv = sIv[e];
        float4 a = *(const float4*)&Up[(size_t)iu * 128 + c0];
        float4 b = *(const float4*)&Vp[(size_t)iv * 128 + c0];
        acc[i][0] = a.x + b.x;
        acc[i][1] = a.y + b.y;
        acc[i][2] = a.z + b.z;
        acc[i][3] = a.w + b.w;
    }
    __syncthreads();   // sEv visible

    // ev @ We (We streamed from global) + bias -> h1
    {
        const float4 b1 = *(const float4*)&sB1[c0];
#pragma unroll
        for (int i = 0; i < 8; ++i) {
            acc[i][0] += b1.x; acc[i][1] += b1.y;
            acc[i][2] += b1.z; acc[i][3] += b1.w;
        }
#pragma unroll
        for (int k = 0; k < 16; ++k) {
            float4 w = *(const float4*)&gw1e[k * 128 + c0];
#pragma unroll
            for (int i = 0; i < 8; ++i) {
                float x = sEv[(rg * 8 + i) * 16 + k];
                acc[i][0] += x * w.x; acc[i][1] += x * w.y;
                acc[i][2] += x * w.z; acc[i][3] += x * w.w;
            }
        }
#pragma unroll
        for (int i = 0; i < 8; ++i) {
            int e = rg * 8 + i;
            float4 h = make_float4(relu(acc[i][0]), relu(acc[i][1]),
                                   relu(acc[i][2]), relu(acc[i][3]));
            *(float4*)&sH1[e * 132 + c0] = h;
        }
    }
    __syncthreads();

    // ---- layer 2: thread = 4 edges x 4 cols; W2 streamed from global ----
    const int cg2 = tid & 15, rg2 = tid >> 4;
    const int c02 = cg2 * 4;
    float acc2[4][4];
    {
        const float4 b2 = *(const float4*)&gb2[c02];
#pragma unroll
        for (int i = 0; i < 4; ++i) {
            acc2[i][0] = b2.x; acc2[i][1] = b2.y;
            acc2[i][2] = b2.z; acc2[i][3] = b2.w;
        }
#pragma unroll 4
        for (int k = 0; k < 128; ++k) {
            float4 w = *(const float4*)&gw2[k * 64 + c02];
#pragma unroll
            for (int i = 0; i < 4; ++i) {
                float h = sH1[(rg2 * 4 + i) * 132 + k];
                acc2[i][0] += h * w.x; acc2[i][1] += h * w.y;
                acc2[i][2] += h * w.z; acc2[i][3] += h * w.w;
            }
        }
    }
    __syncthreads();   // everyone done READING sH1; safe to overwrite

    // write h2 = relu(acc2) into LDS as [64 edges][stride 68]
    float* sH2 = sH1;
#pragma unroll
    for (int i = 0; i < 4; ++i) {
        int e = rg2 * 4 + i;
        float4 h = make_float4(relu(acc2[i][0]), relu(acc2[i][1]),
                               relu(acc2[i][2]), relu(acc2[i][3]));
        *(float4*)&sH2[e * 68 + c02] = h;
    }
    __syncthreads();

    // ---- segmented reduction over sorted iu: thread = (col, quarter) ----
    {
        const int c = tid & 63;       // output column
        const int q = tid >> 6;       // quarter: 16 edges
        const int eq0 = q * 16;
        int   iu_cur = sIu[eq0];
        float running = 0.f;
#pragma unroll
        for (int k = 0; k < 16; ++k) {
            int e = eq0 + k;
            int iu = sIu[e];
            if (iu != iu_cur) {
                atomicAdd(&agg[(size_t)iu_cur * 64 + c], running);
                running = 0.f;
                iu_cur = iu;
            }
            running += sH2[e * 68 + c];
        }
        atomicAdd(&agg[(size_t)iu_cur * 64 + c], running);
    }
}

// ---------------------------------------------------------------------------
// node kernel: out = relu(relu([u, agg] @ fw1 + fb1) @ fw2 + fb2)
// ---------------------------------------------------------------------------
__global__ __launch_bounds__(256) void node_kernel(
    const float* __restrict__ u, const float* __restrict__ agg,
    const float* __restrict__ fw1, const float* __restrict__ fb1,
    const float* __restrict__ fw2, const float* __restrict__ fb2,
    float* __restrict__ out, int N)
{
    __shared__ float sX[64 * 128];  // 32 KB
    __shared__ float sY[64 * 132];  // 33 KB
    const int tid = threadIdx.x;
    const int row0 = blockIdx.x * 64;

    for (int i = tid * 4; i < 64 * 64; i += 1024) {
        int r = i >> 6, c = i & 63;
        int gr = row0 + r;
        float4 uu = (gr < N) ? *(const float4*)&u[(size_t)gr * 64 + c]
                             : make_float4(0.f, 0.f, 0.f, 0.f);
        float4 aa = (gr < N) ? *(const float4*)&agg[(size_t)gr * 64 + c]
                             : make_float4(0.f, 0.f, 0.f, 0.f);
        *(float4*)&sX[r * 128 + c] = uu;
        *(float4*)&sX[r * 128 + 64 + c] = aa;
    }
    __syncthreads();

    {
        const int cg = tid & 31, rg = tid >> 5;
        const int c0 = cg * 4, r0 = rg * 8;
        const float4 b = *(const float4*)&fb1[c0];
        float acc[8][4];
#pragma unroll
        for (int i = 0; i < 8; ++i) {
            acc[i][0] = b.x; acc[i][1] = b.y; acc[i][2] = b.z; acc[i][3] = b.w;
        }
#pragma unroll 4
        for (int k = 0; k < 128; ++k) {
            float4 w = *(const float4*)&fw1[k * 128 + c0];
#pragma unroll
            for (int i = 0; i < 8; ++i) {
                float x = sX[(r0 + i) * 128 + k];
                acc[i][0] += x * w.x; acc[i][1] += x * w.y;
                acc[i][2] += x * w.z; acc[i][3] += x * w.w;
            }
        }
#pragma unroll
        for (int i = 0; i < 8; ++i) {
            float4 h = make_float4(relu(acc[i][0]), relu(acc[i][1]),
                                   relu(acc[i][2]), relu(acc[i][3]));
            *(float4*)&sY[(r0 + i) * 132 + c0] = h;
        }
    }
    __syncthreads();

    {
        const int cg = tid & 15, rg = tid >> 4;
        const int c0 = cg * 4;
        const float4 b = *(const float4*)&fb2[c0];
        float acc[4][4];
#pragma unroll
        for (int i = 0; i < 4; ++i) {
            acc[i][0] = b.x; acc[i][1] = b.y; acc[i][2] = b.z; acc[i][3] = b.w;
        }
#pragma unroll 4
        for (int k = 0; k < 128; ++k) {
            float4 w = *(const float4*)&fw2[k * 64 + c0];
#pragma unroll
            for (int i = 0; i < 4; ++i) {
                float yv = sY[(rg * 4 + i) * 132 + k];
                acc[i][0] += yv * w.x; acc[i][1] += yv * w.y;
                acc[i][2] += yv * w.z; acc[i][3] += yv * w.w;
            }
        }
#pragma unroll
        for (int i = 0; i < 4; ++i) {
            int gr = row0 + rg * 4 + i;
            if (gr < N) {
                float4 o = make_float4(relu(acc[i][0]), relu(acc[i][1]),
                                       relu(acc[i][2]), relu(acc[i][3]));
                *(float4*)&out[(size_t)gr * 64 + c0] = o;
            }
        }
    }
}

// ---------------------------------------------------------------------------
extern "C" void kernel_launch(void* const* d_in, const int* in_sizes, int n_in,
                              void* d_out, int out_size, void* d_ws, size_t ws_size,
                              hipStream_t stream)
{
    const float* u   = (const float*)d_in[0];
    const float* v   = (const float*)d_in[1];
    const float* ev  = (const float*)d_in[2];
    const int*   eiv = (const int*)d_in[3];
    const int*   eiu = (const int*)d_in[4];
    const float* gw1 = (const float*)d_in[5];   // 144 x 128
    const float* gb1 = (const float*)d_in[6];   // 128
    const float* gw2 = (const float*)d_in[7];   // 128 x 64
    const float* gb2 = (const float*)d_in[8];   // 64
    const float* fw1 = (const float*)d_in[9];   // 128 x 128
    const float* fb1 = (const float*)d_in[10];  // 128
    const float* fw2 = (const float*)d_in[11];  // 128 x 64
    const float* fb2 = (const float*)d_in[12];  // 64
    float* out = (float*)d_out;

    // workspace layout (floats/ints are both 4B)
    float* Up     = (float*)d_ws;                    // 50000 x 128
    float* Vp     = Up + (size_t)U_N * 128;          // 50000 x 128
    float* agg    = Vp + (size_t)V_N * 128;          // 50000 x 64
    int*   counts = (int*)(agg + (size_t)U_N * 64);  // 50000
    int*   cursor = counts + U_N;                    // 50000
    int*   perm   = cursor + U_N;                    // 800000

    hipMemsetAsync(counts, 0, U_N * sizeof(int), stream);
    hipMemsetAsync(agg, 0, (size_t)U_N * 64 * sizeof(float), stream);

    dim3 blk(256);
    hist_kernel<<<dim3((E_N + 255) / 256), blk, 0, stream>>>(eiu, counts);
    scan_kernel<<<dim3(1), dim3(1024), 0, stream>>>(counts, cursor);
    permute_kernel<<<dim3((E_N + 255) / 256), blk, 0, stream>>>(eiu, cursor, perm);

    proj_kernel<<<dim3((U_N + 63) / 64), blk, 0, stream>>>(u, gw1, Up, U_N);
    proj_kernel<<<dim3((V_N + 63) / 64), blk, 0, stream>>>(v, gw1 + 64 * 128, Vp, V_N);

    edge_kernel<<<dim3(E_N / 64), blk, 0, stream>>>(
        Up, Vp, ev, eiv, eiu, perm, gw1 + 128 * 128, gb1, gw2, gb2, agg);
    node_kernel<<<dim3((U_N + 63) / 64), blk, 0, stream>>>(
        u, agg, fw1, fb1, fw2, fb2, out, U_N);
}

// Round 4
// 405.972 us; speedup vs baseline: 2.1290x; 1.3609x over previous
//
#include <hip/hip_runtime.h>

// Problem constants (match reference)
constexpr int U_N = 50000;
constexpr int V_N = 50000;
constexpr int E_N = 800000;   // == 64 * 12500, no tail in edge kernel
// dims: F=64, G=64, H=16; g: 144->128->64; f: 128->128->64

typedef float f32x4 __attribute__((ext_vector_type(4)));
typedef short bf16x8 __attribute__((ext_vector_type(8)));

__device__ __forceinline__ float relu(float x) { return fmaxf(x, 0.f); }

// round-to-nearest-even fp32 -> bf16 bits
__device__ __forceinline__ unsigned short f2bf(float f) {
    unsigned u = __float_as_uint(f);
    unsigned rounding = 0x7FFFu + ((u >> 16) & 1u);
    return (unsigned short)((u + rounding) >> 16);
}
__device__ __forceinline__ float bf2f(unsigned short b) {
    return __uint_as_float(((unsigned)b) << 16);
}

// ---------------------------------------------------------------------------
// Counting sort of edges by idx_u: histogram -> exclusive scan -> permutation
// ---------------------------------------------------------------------------
__global__ __launch_bounds__(256) void hist_kernel(const int* __restrict__ idx_u,
                                                   int* __restrict__ counts)
{
    int e = blockIdx.x * 256 + threadIdx.x;
    if (e < E_N) atomicAdd(&counts[idx_u[e]], 1);
}

__global__ __launch_bounds__(1024) void scan_kernel(const int* __restrict__ counts,
                                                    int* __restrict__ cursor)
{
    __shared__ int sPart[1024];
    const int tid = threadIdx.x;
    constexpr int CH = 49;          // 1024*49 = 50176 >= 50000
    const int base = tid * CH;

    int sum = 0;
#pragma unroll
    for (int k = 0; k < CH; ++k) {
        int i = base + k;
        if (i < U_N) sum += counts[i];
    }
    sPart[tid] = sum;
    __syncthreads();
    for (int off = 1; off < 1024; off <<= 1) {
        int v = (tid >= off) ? sPart[tid - off] : 0;
        __syncthreads();
        sPart[tid] += v;
        __syncthreads();
    }
    int run = sPart[tid] - sum;     // exclusive prefix for this chunk
    for (int k = 0; k < CH; ++k) {
        int i = base + k;
        if (i < U_N) { cursor[i] = run; run += counts[i]; }
    }
}

__global__ __launch_bounds__(256) void permute_kernel(const int* __restrict__ idx_u,
                                                      int* __restrict__ cursor,
                                                      int* __restrict__ perm)
{
    int e = blockIdx.x * 256 + threadIdx.x;
    if (e < E_N) {
        int pos = atomicAdd(&cursor[idx_u[e]], 1);
        perm[pos] = e;
    }
}

// ---------------------------------------------------------------------------
// W2 -> bf16 fragment-major layout: W2f[((ks*4+nt)*64+lane)*8+j]
//   n = nt*16 + (lane&15); k = ks*32 + (lane>>4)*8 + j
// ---------------------------------------------------------------------------
__global__ __launch_bounds__(256) void w2f_prep(const float* __restrict__ gw2,
                                                unsigned short* __restrict__ W2f)
{
    int t = blockIdx.x * 256 + threadIdx.x;   // 0 .. 8191
    if (t >= 4 * 4 * 64 * 8) return;
    int j    = t & 7;
    int lane = (t >> 3) & 63;
    int nt   = (t >> 9) & 3;
    int ks   = t >> 11;
    int n = nt * 16 + (lane & 15);
    int k = ks * 32 + (lane >> 4) * 8 + j;
    W2f[t] = f2bf(gw2[k * 64 + n]);
}

// ---------------------------------------------------------------------------
// proj: P[N][128] = X[N][64] @ W[64][128]; output fp32 (Up) or bf16 (Vp)
// ---------------------------------------------------------------------------
template <bool BF16OUT>
__global__ __launch_bounds__(256) void proj_kernel(const float* __restrict__ X,
                                                   const float* __restrict__ W,
                                                   void* __restrict__ P, int N)
{
    __shared__ float sW[64 * 128];  // 32 KB
    __shared__ float sX[64 * 64];   // 16 KB
    const int tid = threadIdx.x;
    const int row0 = blockIdx.x * 64;

    for (int i = tid * 4; i < 64 * 128; i += 1024)
        *(float4*)&sW[i] = *(const float4*)&W[i];
    for (int i = tid * 4; i < 64 * 64; i += 1024) {
        int r = i >> 6, c = i & 63;
        int gr = row0 + r;
        float4 val = (gr < N) ? *(const float4*)&X[(size_t)gr * 64 + c]
                              : make_float4(0.f, 0.f, 0.f, 0.f);
        *(float4*)&sX[i] = val;
    }
    __syncthreads();

    const int cg = tid & 31, rg = tid >> 5;
    const int c0 = cg * 4, r0 = rg * 8;
    float acc[8][4];
#pragma unroll
    for (int i = 0; i < 8; ++i)
#pragma unroll
        for (int j = 0; j < 4; ++j) acc[i][j] = 0.f;

#pragma unroll 4
    for (int k = 0; k < 64; ++k) {
        float4 w = *(const float4*)&sW[k * 128 + c0];
#pragma unroll
        for (int i = 0; i < 8; ++i) {
            float x = sX[(r0 + i) * 64 + k];
            acc[i][0] += x * w.x; acc[i][1] += x * w.y;
            acc[i][2] += x * w.z; acc[i][3] += x * w.w;
        }
    }
#pragma unroll
    for (int i = 0; i < 8; ++i) {
        int gr = row0 + r0 + i;
        if (gr < N) {
            if (BF16OUT) {
                ushort4 o;
                o.x = f2bf(acc[i][0]); o.y = f2bf(acc[i][1]);
                o.z = f2bf(acc[i][2]); o.w = f2bf(acc[i][3]);
                *(ushort4*)&((unsigned short*)P)[(size_t)gr * 128 + c0] = o;
            } else {
                float4 o = make_float4(acc[i][0], acc[i][1], acc[i][2], acc[i][3]);
                *(float4*)&((float*)P)[(size_t)gr * 128 + c0] = o;
            }
        }
    }
}

// ---------------------------------------------------------------------------
// edge kernel over SORTED edges: per 64-edge tile, 4 waves, wave-local rows
//   h1 = relu(Up[iu] + Vp[iv] + ev @ We + b1)   (VALU, fp32 acc) -> bf16 LDS
//   h2 = relu(h1 @ W2 + b2)                     (MFMA 16x16x32 bf16)
//   segmented sum of h2 over runs of equal iu -> few atomics into agg
// LDS ~= 23 KB.
// ---------------------------------------------------------------------------
__global__ __launch_bounds__(256, 4) void edge_kernel(
    const float* __restrict__ Up,            // 50000 x 128 fp32
    const unsigned short* __restrict__ Vp,   // 50000 x 128 bf16
    const float* __restrict__ ev, const int* __restrict__ idx_v,
    const int* __restrict__ idx_u, const int* __restrict__ perm,
    const float* __restrict__ gw1e,          // 16 x 128 (rows 128..143 of g_w1)
    const float* __restrict__ gb1,
    const unsigned short* __restrict__ W2f,  // fragment-major bf16 W2
    const float* __restrict__ gb2,
    float* __restrict__ agg)
{
    __shared__ unsigned short sH1[64 * 136];  // 17408 B; aliased as sH2 fp32 [64][68]
    __shared__ float sEv[64 * 16];            // 4 KB
    __shared__ float sB1[128];
    __shared__ int   sIu[64];
    __shared__ int   sIv[64];
    __shared__ int   sPerm[64];

    const int tid = threadIdx.x;
    const int e0 = blockIdx.x * 64;

    if (tid < 64) {
        int p = perm[e0 + tid];
        sPerm[tid] = p;
        sIu[tid] = idx_u[p];
        sIv[tid] = idx_v[p];
    } else if (tid < 96) {
        int j = (tid - 64) * 4;
        *(float4*)&sB1[j] = *(const float4*)&gb1[j];
    }
    __syncthreads();

    // --- stage ev rows (gathered via perm) ---
    {
        int i = tid * 4;  // exactly 1024 floats with 256 threads
        int e = i >> 4, k = i & 15;
        *(float4*)&sEv[i] = *(const float4*)&ev[(size_t)sPerm[e] * 16 + k];
    }

    // --- layer-1 mapping: thread = 8 edges x 4 cols (wave-local rows) ---
    const int cg = tid & 31, rg = tid >> 5;
    const int c0 = cg * 4;

    float acc[8][4];
#pragma unroll
    for (int i = 0; i < 8; ++i) {
        int e = rg * 8 + i;
        int iu = sIu[e];
        int iv = sIv[e];
        float4 a = *(const float4*)&Up[(size_t)iu * 128 + c0];
        ushort4 bv = *(const ushort4*)&Vp[(size_t)iv * 128 + c0];
        acc[i][0] = a.x + bf2f(bv.x);
        acc[i][1] = a.y + bf2f(bv.y);
        acc[i][2] = a.z + bf2f(bv.z);
        acc[i][3] = a.w + bf2f(bv.w);
    }
    __syncthreads();   // sEv visible

    // ev @ We (We streamed from global) + bias -> h1 (bf16 in LDS, pad 136)
    {
        const float4 b1 = *(const float4*)&sB1[c0];
#pragma unroll
        for (int i = 0; i < 8; ++i) {
            acc[i][0] += b1.x; acc[i][1] += b1.y;
            acc[i][2] += b1.z; acc[i][3] += b1.w;
        }
#pragma unroll
        for (int k = 0; k < 16; ++k) {
            float4 w = *(const float4*)&gw1e[k * 128 + c0];
#pragma unroll
            for (int i = 0; i < 8; ++i) {
                float x = sEv[(rg * 8 + i) * 16 + k];
                acc[i][0] += x * w.x; acc[i][1] += x * w.y;
                acc[i][2] += x * w.z; acc[i][3] += x * w.w;
            }
        }
#pragma unroll
        for (int i = 0; i < 8; ++i) {
            int e = rg * 8 + i;
            ushort4 h;
            h.x = f2bf(relu(acc[i][0]));
            h.y = f2bf(relu(acc[i][1]));
            h.z = f2bf(relu(acc[i][2]));
            h.w = f2bf(relu(acc[i][3]));
            *(ushort4*)&sH1[e * 136 + c0] = h;
        }
    }
    __syncthreads();

    // ---- layer 2 via MFMA: wave w owns edges 16w..16w+15 ----
    const int wid = tid >> 6, lane = tid & 63;
    f32x4 accm[4];
#pragma unroll
    for (int nt = 0; nt < 4; ++nt)
#pragma unroll
        for (int r = 0; r < 4; ++r) accm[nt][r] = 0.f;

#pragma unroll
    for (int ks = 0; ks < 4; ++ks) {
        bf16x8 a = *(const bf16x8*)&sH1[(wid * 16 + (lane & 15)) * 136 +
                                        ks * 32 + (lane >> 4) * 8];
#pragma unroll
        for (int nt = 0; nt < 4; ++nt) {
            bf16x8 b = *(const bf16x8*)&W2f[(size_t)(((ks * 4 + nt) * 64 + lane) * 8)];
            accm[nt] = __builtin_amdgcn_mfma_f32_16x16x32_bf16(a, b, accm[nt], 0, 0, 0);
        }
    }
    __syncthreads();   // all sH1 fragment reads done; reuse region as sH2

    float* sH2 = (float*)sH1;   // [64][68] fp32 == 17408 B, same size
#pragma unroll
    for (int nt = 0; nt < 4; ++nt) {
        int col = nt * 16 + (lane & 15);
        float b2v = gb2[col];
        int erow = wid * 16 + (lane >> 4) * 4;
#pragma unroll
        for (int r = 0; r < 4; ++r)
            sH2[(erow + r) * 68 + col] = relu(accm[nt][r] + b2v);
    }
    __syncthreads();

    // ---- segmented reduction over sorted iu: thread = (col, quarter) ----
    {
        const int c = tid & 63;       // output column
        const int q = tid >> 6;       // quarter: 16 edges (== this wave's rows)
        const int eq0 = q * 16;
        int   iu_cur = sIu[eq0];
        float running = 0.f;
#pragma unroll
        for (int k = 0; k < 16; ++k) {
            int e = eq0 + k;
            int iu = sIu[e];
            if (iu != iu_cur) {
                atomicAdd(&agg[(size_t)iu_cur * 64 + c], running);
                running = 0.f;
                iu_cur = iu;
            }
            running += sH2[e * 68 + c];
        }
        atomicAdd(&agg[(size_t)iu_cur * 64 + c], running);
    }
}

// ---------------------------------------------------------------------------
// node kernel: out = relu(relu([u, agg] @ fw1 + fb1) @ fw2 + fb2)
// ---------------------------------------------------------------------------
__global__ __launch_bounds__(256) void node_kernel(
    const float* __restrict__ u, const float* __restrict__ agg,
    const float* __restrict__ fw1, const float* __restrict__ fb1,
    const float* __restrict__ fw2, const float* __restrict__ fb2,
    float* __restrict__ out, int N)
{
    __shared__ float sX[64 * 128];  // 32 KB
    __shared__ float sY[64 * 132];  // 33 KB
    const int tid = threadIdx.x;
    const int row0 = blockIdx.x * 64;

    for (int i = tid * 4; i < 64 * 64; i += 1024) {
        int r = i >> 6, c = i & 63;
        int gr = row0 + r;
        float4 uu = (gr < N) ? *(const float4*)&u[(size_t)gr * 64 + c]
                             : make_float4(0.f, 0.f, 0.f, 0.f);
        float4 aa = (gr < N) ? *(const float4*)&agg[(size_t)gr * 64 + c]
                             : make_float4(0.f, 0.f, 0.f, 0.f);
        *(float4*)&sX[r * 128 + c] = uu;
        *(float4*)&sX[r * 128 + 64 + c] = aa;
    }
    __syncthreads();

    {
        const int cg = tid & 31, rg = tid >> 5;
        const int c0 = cg * 4, r0 = rg * 8;
        const float4 b = *(const float4*)&fb1[c0];
        float acc[8][4];
#pragma unroll
        for (int i = 0; i < 8; ++i) {
            acc[i][0] = b.x; acc[i][1] = b.y; acc[i][2] = b.z; acc[i][3] = b.w;
        }
#pragma unroll 4
        for (int k = 0; k < 128; ++k) {
            float4 w = *(const float4*)&fw1[k * 128 + c0];
#pragma unroll
            for (int i = 0; i < 8; ++i) {
                float x = sX[(r0 + i) * 128 + k];
                acc[i][0] += x * w.x; acc[i][1] += x * w.y;
                acc[i][2] += x * w.z; acc[i][3] += x * w.w;
            }
        }
#pragma unroll
        for (int i = 0; i < 8; ++i) {
            float4 h = make_float4(relu(acc[i][0]), relu(acc[i][1]),
                                   relu(acc[i][2]), relu(acc[i][3]));
            *(float4*)&sY[(r0 + i) * 132 + c0] = h;
        }
    }
    __syncthreads();

    {
        const int cg = tid & 15, rg = tid >> 4;
        const int c0 = cg * 4;
        const float4 b = *(const float4*)&fb2[c0];
        float acc[4][4];
#pragma unroll
        for (int i = 0; i < 4; ++i) {
            acc[i][0] = b.x; acc[i][1] = b.y; acc[i][2] = b.z; acc[i][3] = b.w;
        }
#pragma unroll 4
        for (int k = 0; k < 128; ++k) {
            float4 w = *(const float4*)&fw2[k * 64 + c0];
#pragma unroll
            for (int i = 0; i < 4; ++i) {
                float yv = sY[(rg * 4 + i) * 132 + k];
                acc[i][0] += yv * w.x; acc[i][1] += yv * w.y;
                acc[i][2] += yv * w.z; acc[i][3] += yv * w.w;
            }
        }
#pragma unroll
        for (int i = 0; i < 4; ++i) {
            int gr = row0 + rg * 4 + i;
            if (gr < N) {
                float4 o = make_float4(relu(acc[i][0]), relu(acc[i][1]),
                                       relu(acc[i][2]), relu(acc[i][3]));
                *(float4*)&out[(size_t)gr * 64 + c0] = o;
            }
        }
    }
}

// ---------------------------------------------------------------------------
extern "C" void kernel_launch(void* const* d_in, const int* in_sizes, int n_in,
                              void* d_out, int out_size, void* d_ws, size_t ws_size,
                              hipStream_t stream)
{
    const float* u   = (const float*)d_in[0];
    const float* v   = (const float*)d_in[1];
    const float* ev  = (const float*)d_in[2];
    const int*   eiv = (const int*)d_in[3];
    const int*   eiu = (const int*)d_in[4];
    const float* gw1 = (const float*)d_in[5];   // 144 x 128
    const float* gb1 = (const float*)d_in[6];   // 128
    const float* gw2 = (const float*)d_in[7];   // 128 x 64
    const float* gb2 = (const float*)d_in[8];   // 64
    const float* fw1 = (const float*)d_in[9];   // 128 x 128
    const float* fb1 = (const float*)d_in[10];  // 128
    const float* fw2 = (const float*)d_in[11];  // 128 x 64
    const float* fb2 = (const float*)d_in[12];  // 64
    float* out = (float*)d_out;

    // workspace layout (4-byte units)
    float*          Up     = (float*)d_ws;                        // 50000x128 f32
    unsigned short* Vp     = (unsigned short*)(Up + (size_t)U_N * 128);  // 50000x128 bf16
    float*          agg    = (float*)(Vp + (size_t)V_N * 128);    // 50000x64 f32
    int*            counts = (int*)(agg + (size_t)U_N * 64);      // 50000
    int*            cursor = counts + U_N;                        // 50000
    int*            perm   = cursor + U_N;                        // 800000
    unsigned short* W2f    = (unsigned short*)(perm + E_N);       // 8192 bf16

    hipMemsetAsync(counts, 0, U_N * sizeof(int), stream);
    hipMemsetAsync(agg, 0, (size_t)U_N * 64 * sizeof(float), stream);

    dim3 blk(256);
    hist_kernel<<<dim3((E_N + 255) / 256), blk, 0, stream>>>(eiu, counts);
    scan_kernel<<<dim3(1), dim3(1024), 0, stream>>>(counts, cursor);
    permute_kernel<<<dim3((E_N + 255) / 256), blk, 0, stream>>>(eiu, cursor, perm);

    proj_kernel<false><<<dim3((U_N + 63) / 64), blk, 0, stream>>>(u, gw1, Up, U_N);
    proj_kernel<true ><<<dim3((V_N + 63) / 64), blk, 0, stream>>>(v, gw1 + 64 * 128, Vp, V_N);
    w2f_prep<<<dim3(32), blk, 0, stream>>>(gw2, W2f);

    edge_kernel<<<dim3(E_N / 64), blk, 0, stream>>>(
        Up, Vp, ev, eiv, eiu, perm, gw1 + 128 * 128, gb1, W2f, gb2, agg);
    node_kernel<<<dim3((U_N + 63) / 64), blk, 0, stream>>>(
        u, agg, fw1, fb1, fw2, fb2, out, U_N);
}

// Round 5
// 392.862 us; speedup vs baseline: 2.2001x; 1.0334x over previous
//
#include <hip/hip_runtime.h>

// Problem constants (match reference)
constexpr int U_N = 50000;
constexpr int V_N = 50000;
constexpr int E_N = 800000;   // == 64 * 12500, no tail in edge kernel
// dims: F=64, G=64, H=16; g: 144->128->64; f: 128->128->64

typedef float f32x4 __attribute__((ext_vector_type(4)));
typedef short bf16x8 __attribute__((ext_vector_type(8)));

__device__ __forceinline__ float relu(float x) { return fmaxf(x, 0.f); }

// round-to-nearest-even fp32 -> bf16 bits
__device__ __forceinline__ unsigned short f2bf(float f) {
    unsigned u = __float_as_uint(f);
    unsigned rounding = 0x7FFFu + ((u >> 16) & 1u);
    return (unsigned short)((u + rounding) >> 16);
}
__device__ __forceinline__ float bf2f(unsigned short b) {
    return __uint_as_float(((unsigned)b) << 16);
}

// ---------------------------------------------------------------------------
// Counting sort of edges by idx_u: histogram -> exclusive scan -> permutation
// ---------------------------------------------------------------------------
__global__ __launch_bounds__(256) void hist_kernel(const int* __restrict__ idx_u,
                                                   int* __restrict__ counts)
{
    int e = blockIdx.x * 256 + threadIdx.x;
    if (e < E_N) atomicAdd(&counts[idx_u[e]], 1);
}

__global__ __launch_bounds__(1024) void scan_kernel(const int* __restrict__ counts,
                                                    int* __restrict__ cursor)
{
    __shared__ int sPart[1024];
    const int tid = threadIdx.x;
    constexpr int CH = 49;          // 1024*49 = 50176 >= 50000
    const int base = tid * CH;

    int sum = 0;
#pragma unroll
    for (int k = 0; k < CH; ++k) {
        int i = base + k;
        if (i < U_N) sum += counts[i];
    }
    sPart[tid] = sum;
    __syncthreads();
    for (int off = 1; off < 1024; off <<= 1) {
        int v = (tid >= off) ? sPart[tid - off] : 0;
        __syncthreads();
        sPart[tid] += v;
        __syncthreads();
    }
    int run = sPart[tid] - sum;     // exclusive prefix for this chunk
    for (int k = 0; k < CH; ++k) {
        int i = base + k;
        if (i < U_N) { cursor[i] = run; run += counts[i]; }
    }
}

__global__ __launch_bounds__(256) void permute_kernel(const int* __restrict__ idx_u,
                                                      int* __restrict__ cursor,
                                                      int* __restrict__ perm)
{
    int e = blockIdx.x * 256 + threadIdx.x;
    if (e < E_N) {
        int pos = atomicAdd(&cursor[idx_u[e]], 1);
        perm[pos] = e;
    }
}

// ---------------------------------------------------------------------------
// proj body: P[row0..row0+64][128] = X @ W (64x128), fp32 or bf16 output
// ---------------------------------------------------------------------------
template <bool BF16OUT>
__device__ __forceinline__ void proj_body(const float* __restrict__ X,
                                          const float* __restrict__ W,
                                          void* __restrict__ P, int N, int row0,
                                          float* sW, float* sX)
{
    const int tid = threadIdx.x;

    for (int i = tid * 4; i < 64 * 128; i += 1024)
        *(float4*)&sW[i] = *(const float4*)&W[i];
    for (int i = tid * 4; i < 64 * 64; i += 1024) {
        int r = i >> 6, c = i & 63;
        int gr = row0 + r;
        float4 val = (gr < N) ? *(const float4*)&X[(size_t)gr * 64 + c]
                              : make_float4(0.f, 0.f, 0.f, 0.f);
        *(float4*)&sX[i] = val;
    }
    __syncthreads();

    const int cg = tid & 31, rg = tid >> 5;
    const int c0 = cg * 4, r0 = rg * 8;
    float acc[8][4];
#pragma unroll
    for (int i = 0; i < 8; ++i)
#pragma unroll
        for (int j = 0; j < 4; ++j) acc[i][j] = 0.f;

#pragma unroll 4
    for (int k = 0; k < 64; ++k) {
        float4 w = *(const float4*)&sW[k * 128 + c0];
#pragma unroll
        for (int i = 0; i < 8; ++i) {
            float x = sX[(r0 + i) * 64 + k];
            acc[i][0] += x * w.x; acc[i][1] += x * w.y;
            acc[i][2] += x * w.z; acc[i][3] += x * w.w;
        }
    }
#pragma unroll
    for (int i = 0; i < 8; ++i) {
        int gr = row0 + r0 + i;
        if (gr < N) {
            if (BF16OUT) {
                ushort4 o;
                o.x = f2bf(acc[i][0]); o.y = f2bf(acc[i][1]);
                o.z = f2bf(acc[i][2]); o.w = f2bf(acc[i][3]);
                *(ushort4*)&((unsigned short*)P)[(size_t)gr * 128 + c0] = o;
            } else {
                float4 o = make_float4(acc[i][0], acc[i][1], acc[i][2], acc[i][3]);
                *(float4*)&((float*)P)[(size_t)gr * 128 + c0] = o;
            }
        }
    }
}

// ---------------------------------------------------------------------------
// prep kernel: blocks [0,782) projU (fp32), [782,1564) projV (bf16),
//              block 1564 packs W2f (layer-2 B-frags) and Wef (layer-1 A-frags)
// W2f[((ks*4+nt)*64+lane)*8+j]:  n=nt*16+(lane&15), k=ks*32+(lane>>4)*8+j  (128x64 W2)
// Wef[(ct*64+lane)*8+j]:        c=ct*16+(lane&15), k=(lane>>4)*8+j, 0 for k>=16
//                                (We^T fragments; We = gw1 rows 128..143, 16x128)
// ---------------------------------------------------------------------------
constexpr int NB_PROJ = (U_N + 63) / 64;   // 782

__global__ __launch_bounds__(256) void prep_kernel(
    const float* __restrict__ u, const float* __restrict__ v,
    const float* __restrict__ gw1, const float* __restrict__ gw2,
    float* __restrict__ Up, unsigned short* __restrict__ Vp,
    unsigned short* __restrict__ W2f, unsigned short* __restrict__ Wef)
{
    __shared__ float sW[64 * 128];
    __shared__ float sX[64 * 64];
    const int b = blockIdx.x;

    if (b < NB_PROJ) {
        proj_body<false>(u, gw1, Up, U_N, b * 64, sW, sX);
    } else if (b < 2 * NB_PROJ) {
        proj_body<true>(v, gw1 + 64 * 128, Vp, V_N, (b - NB_PROJ) * 64, sW, sX);
    } else {
        const int tid = threadIdx.x;
        // W2f: 8192 elements
        for (int t = tid; t < 4 * 4 * 64 * 8; t += 256) {
            int j    = t & 7;
            int lane = (t >> 3) & 63;
            int nt   = (t >> 9) & 3;
            int ks   = t >> 11;
            int n = nt * 16 + (lane & 15);
            int k = ks * 32 + (lane >> 4) * 8 + j;
            W2f[t] = f2bf(gw2[k * 64 + n]);
        }
        // Wef: 4096 elements (We^T frags, K padded to 32)
        const float* gw1e = gw1 + 128 * 128;   // 16 x 128
        for (int t = tid; t < 8 * 64 * 8; t += 256) {
            int j    = t & 7;
            int lane = (t >> 3) & 63;
            int ct   = t >> 9;
            int c = ct * 16 + (lane & 15);
            int k = (lane >> 4) * 8 + j;
            Wef[t] = (k < 16) ? f2bf(gw1e[k * 128 + c]) : (unsigned short)0;
        }
    }
}

// ---------------------------------------------------------------------------
// edge kernel over SORTED edges: 64 edges/block, 4 waves, 16 edges/wave.
// layer 1 (MFMA, transposed): acc[ct] = (We^T @ ev^T) tiles; D[c][e] layout
//   gives each lane 4 consecutive cols of ONE edge -> float4 Up/Vp/b1 add.
// layer 2 (MFMA): h2 = relu(h1 @ W2 + b2); segmented-sum -> few atomics.
// All LDS rows are wave-local; only barrier needs: sIu staging + alias switch.
// ---------------------------------------------------------------------------
__global__ __launch_bounds__(256, 6) void edge_kernel(
    const float* __restrict__ Up,            // 50000 x 128 fp32
    const unsigned short* __restrict__ Vp,   // 50000 x 128 bf16
    const float* __restrict__ ev, const int* __restrict__ idx_v,
    const int* __restrict__ idx_u, const int* __restrict__ perm,
    const unsigned short* __restrict__ Wef,  // layer-1 A frags (We^T, K=32 pad)
    const float* __restrict__ gb1,
    const unsigned short* __restrict__ W2f,  // layer-2 B frags
    const float* __restrict__ gb2,
    float* __restrict__ agg)
{
    __shared__ unsigned short sH1[64 * 136];  // 17408 B; aliased as sH2 f32 [64][68]
    __shared__ int sIu[64];

    const int tid = threadIdx.x;
    const int e0 = blockIdx.x * 64;
    const int wid = tid >> 6, lane = tid & 63;
    const int lo = lane & 15, hi = lane >> 4;

    if (tid < 64) sIu[tid] = idx_u[perm[e0 + tid]];   // for segmented reduce

    // ---- layer 1: this lane's edge = wid*16+lo (same edge for all ct) ----
    const int p  = perm[e0 + wid * 16 + lo];          // 4 lanes share -> broadcast
    const int iu = idx_u[p];
    const int iv = idx_v[p];

    // B-frag: ev[p][k], k=(hi)*8+j ; zeros for k>=16
    bf16x8 bfrag;
    if (hi < 2) {
        float4 x0 = *(const float4*)&ev[(size_t)p * 16 + hi * 8];
        float4 x1 = *(const float4*)&ev[(size_t)p * 16 + hi * 8 + 4];
        union { bf16x8 v; unsigned short s[8]; } r;
        r.s[0] = f2bf(x0.x); r.s[1] = f2bf(x0.y); r.s[2] = f2bf(x0.z); r.s[3] = f2bf(x0.w);
        r.s[4] = f2bf(x1.x); r.s[5] = f2bf(x1.y); r.s[6] = f2bf(x1.z); r.s[7] = f2bf(x1.w);
        bfrag = r.v;
    } else {
        bfrag = (bf16x8)(short)0;
    }

    f32x4 acc[8];
#pragma unroll
    for (int ct = 0; ct < 8; ++ct) {
#pragma unroll
        for (int r = 0; r < 4; ++r) acc[ct][r] = 0.f;
        bf16x8 a = *(const bf16x8*)&Wef[(size_t)((ct * 64 + lane) * 8)];
        acc[ct] = __builtin_amdgcn_mfma_f32_16x16x32_bf16(a, bfrag, acc[ct], 0, 0, 0);
    }

    // epilogue: h1 = relu(acc + b1 + Up[iu] + Vp[iv]) -> bf16 LDS (wave-local rows)
    const int e_loc = wid * 16 + lo;
#pragma unroll
    for (int ct = 0; ct < 8; ++ct) {
        int c0 = ct * 16 + hi * 4;
        float4 up = *(const float4*)&Up[(size_t)iu * 128 + c0];
        ushort4 vp = *(const ushort4*)&Vp[(size_t)iv * 128 + c0];
        float4 b1 = *(const float4*)&gb1[c0];
        ushort4 h;
        h.x = f2bf(relu(acc[ct][0] + b1.x + up.x + bf2f(vp.x)));
        h.y = f2bf(relu(acc[ct][1] + b1.y + up.y + bf2f(vp.y)));
        h.z = f2bf(relu(acc[ct][2] + b1.z + up.z + bf2f(vp.z)));
        h.w = f2bf(relu(acc[ct][3] + b1.w + up.w + bf2f(vp.w)));
        *(ushort4*)&sH1[e_loc * 136 + c0] = h;
    }
    // intra-wave LDS write->read (same type family): no barrier needed

    // ---- layer 2 via MFMA: wave reads its OWN 16 rows of sH1 ----
    f32x4 accm[4];
#pragma unroll
    for (int nt = 0; nt < 4; ++nt)
#pragma unroll
        for (int r = 0; r < 4; ++r) accm[nt][r] = 0.f;

#pragma unroll
    for (int ks = 0; ks < 4; ++ks) {
        bf16x8 a = *(const bf16x8*)&sH1[(wid * 16 + lo) * 136 + ks * 32 + hi * 8];
#pragma unroll
        for (int nt = 0; nt < 4; ++nt) {
            bf16x8 b = *(const bf16x8*)&W2f[(size_t)(((ks * 4 + nt) * 64 + lane) * 8)];
            accm[nt] = __builtin_amdgcn_mfma_f32_16x16x32_bf16(a, b, accm[nt], 0, 0, 0);
        }
    }
    __syncthreads();   // sIu visible + ushort->float alias boundary

    float* sH2 = (float*)sH1;   // [64][68] fp32, same 272B row stride (wave-local)
#pragma unroll
    for (int nt = 0; nt < 4; ++nt) {
        int col = nt * 16 + lo;
        float b2v = gb2[col];
        int erow = wid * 16 + hi * 4;
#pragma unroll
        for (int r = 0; r < 4; ++r)
            sH2[(erow + r) * 68 + col] = relu(accm[nt][r] + b2v);
    }
    __syncthreads();

    // ---- segmented reduction over sorted iu: thread = (col, quarter) ----
    {
        const int c = tid & 63;       // output column
        const int q = tid >> 6;       // quarter: this wave's 16 edges
        const int eq0 = q * 16;
        int   iu_cur = sIu[eq0];
        float running = 0.f;
#pragma unroll
        for (int k = 0; k < 16; ++k) {
            int e = eq0 + k;
            int iu2 = sIu[e];
            if (iu2 != iu_cur) {
                atomicAdd(&agg[(size_t)iu_cur * 64 + c], running);
                running = 0.f;
                iu_cur = iu2;
            }
            running += sH2[e * 68 + c];
        }
        atomicAdd(&agg[(size_t)iu_cur * 64 + c], running);
    }
}

// ---------------------------------------------------------------------------
// node kernel: out = relu(relu([u, agg] @ fw1 + fb1) @ fw2 + fb2)
// ---------------------------------------------------------------------------
__global__ __launch_bounds__(256) void node_kernel(
    const float* __restrict__ u, const float* __restrict__ agg,
    const float* __restrict__ fw1, const float* __restrict__ fb1,
    const float* __restrict__ fw2, const float* __restrict__ fb2,
    float* __restrict__ out, int N)
{
    __shared__ float sX[64 * 128];  // 32 KB
    __shared__ float sY[64 * 132];  // 33 KB
    const int tid = threadIdx.x;
    const int row0 = blockIdx.x * 64;

    for (int i = tid * 4; i < 64 * 64; i += 1024) {
        int r = i >> 6, c = i & 63;
        int gr = row0 + r;
        float4 uu = (gr < N) ? *(const float4*)&u[(size_t)gr * 64 + c]
                             : make_float4(0.f, 0.f, 0.f, 0.f);
        float4 aa = (gr < N) ? *(const float4*)&agg[(size_t)gr * 64 + c]
                             : make_float4(0.f, 0.f, 0.f, 0.f);
        *(float4*)&sX[r * 128 + c] = uu;
        *(float4*)&sX[r * 128 + 64 + c] = aa;
    }
    __syncthreads();

    {
        const int cg = tid & 31, rg = tid >> 5;
        const int c0 = cg * 4, r0 = rg * 8;
        const float4 b = *(const float4*)&fb1[c0];
        float acc[8][4];
#pragma unroll
        for (int i = 0; i < 8; ++i) {
            acc[i][0] = b.x; acc[i][1] = b.y; acc[i][2] = b.z; acc[i][3] = b.w;
        }
#pragma unroll 4
        for (int k = 0; k < 128; ++k) {
            float4 w = *(const float4*)&fw1[k * 128 + c0];
#pragma unroll
            for (int i = 0; i < 8; ++i) {
                float x = sX[(r0 + i) * 128 + k];
                acc[i][0] += x * w.x; acc[i][1] += x * w.y;
                acc[i][2] += x * w.z; acc[i][3] += x * w.w;
            }
        }
#pragma unroll
        for (int i = 0; i < 8; ++i) {
            float4 h = make_float4(relu(acc[i][0]), relu(acc[i][1]),
                                   relu(acc[i][2]), relu(acc[i][3]));
            *(float4*)&sY[(r0 + i) * 132 + c0] = h;
        }
    }
    __syncthreads();

    {
        const int cg = tid & 15, rg = tid >> 4;
        const int c0 = cg * 4;
        const float4 b = *(const float4*)&fb2[c0];
        float acc[4][4];
#pragma unroll
        for (int i = 0; i < 4; ++i) {
            acc[i][0] = b.x; acc[i][1] = b.y; acc[i][2] = b.z; acc[i][3] = b.w;
        }
#pragma unroll 4
        for (int k = 0; k < 128; ++k) {
            float4 w = *(const float4*)&fw2[k * 64 + c0];
#pragma unroll
            for (int i = 0; i < 4; ++i) {
                float yv = sY[(rg * 4 + i) * 132 + k];
                acc[i][0] += yv * w.x; acc[i][1] += yv * w.y;
                acc[i][2] += yv * w.z; acc[i][3] += yv * w.w;
            }
        }
#pragma unroll
        for (int i = 0; i < 4; ++i) {
            int gr = row0 + rg * 4 + i;
            if (gr < N) {
                float4 o = make_float4(relu(acc[i][0]), relu(acc[i][1]),
                                       relu(acc[i][2]), relu(acc[i][3]));
                *(float4*)&out[(size_t)gr * 64 + c0] = o;
            }
        }
    }
}

// ---------------------------------------------------------------------------
extern "C" void kernel_launch(void* const* d_in, const int* in_sizes, int n_in,
                              void* d_out, int out_size, void* d_ws, size_t ws_size,
                              hipStream_t stream)
{
    const float* u   = (const float*)d_in[0];
    const float* v   = (const float*)d_in[1];
    const float* ev  = (const float*)d_in[2];
    const int*   eiv = (const int*)d_in[3];
    const int*   eiu = (const int*)d_in[4];
    const float* gw1 = (const float*)d_in[5];   // 144 x 128
    const float* gb1 = (const float*)d_in[6];   // 128
    const float* gw2 = (const float*)d_in[7];   // 128 x 64
    const float* gb2 = (const float*)d_in[8];   // 64
    const float* fw1 = (const float*)d_in[9];   // 128 x 128
    const float* fb1 = (const float*)d_in[10];  // 128
    const float* fw2 = (const float*)d_in[11];  // 128 x 64
    const float* fb2 = (const float*)d_in[12];  // 64
    float* out = (float*)d_out;

    // workspace layout (agg and counts adjacent -> single memset)
    float*          Up     = (float*)d_ws;                              // 50000x128 f32
    unsigned short* Vp     = (unsigned short*)(Up + (size_t)U_N * 128); // 50000x128 bf16
    float*          agg    = (float*)(Vp + (size_t)V_N * 128);          // 50000x64 f32
    int*            counts = (int*)(agg + (size_t)U_N * 64);            // 50000
    int*            cursor = counts + U_N;                              // 50000
    int*            perm   = cursor + U_N;                              // 800000
    unsigned short* W2f    = (unsigned short*)(perm + E_N);             // 8192 bf16
    unsigned short* Wef    = W2f + 8192;                                // 4096 bf16

    // one memset covers agg (zero init) + counts (hist init)
    hipMemsetAsync(agg, 0, ((size_t)U_N * 64 + U_N) * sizeof(float), stream);

    dim3 blk(256);
    hist_kernel<<<dim3((E_N + 255) / 256), blk, 0, stream>>>(eiu, counts);
    scan_kernel<<<dim3(1), dim3(1024), 0, stream>>>(counts, cursor);
    permute_kernel<<<dim3((E_N + 255) / 256), blk, 0, stream>>>(eiu, cursor, perm);

    prep_kernel<<<dim3(2 * NB_PROJ + 1), blk, 0, stream>>>(
        u, v, gw1, gw2, Up, Vp, W2f, Wef);

    edge_kernel<<<dim3(E_N / 64), blk, 0, stream>>>(
        Up, Vp, ev, eiv, eiu, perm, Wef, gb1, W2f, gb2, agg);
    node_kernel<<<dim3((U_N + 63) / 64), blk, 0, stream>>>(
        u, agg, fw1, fb1, fw2, fb2, out, U_N);
}

// Round 6
// 385.803 us; speedup vs baseline: 2.2403x; 1.0183x over previous
//
#include <hip/hip_runtime.h>

// Problem constants (match reference)
constexpr int U_N = 50000;
constexpr int V_N = 50000;
constexpr int E_N = 800000;   // == 64 * 12500, no tail in edge kernel
// dims: F=64, G=64, H=16; g: 144->128->64; f: 128->128->64

typedef float f32x4 __attribute__((ext_vector_type(4)));
typedef short bf16x8 __attribute__((ext_vector_type(8)));

__device__ __forceinline__ float relu(float x) { return fmaxf(x, 0.f); }

// round-to-nearest-even fp32 -> bf16 bits
__device__ __forceinline__ unsigned short f2bf(float f) {
    unsigned u = __float_as_uint(f);
    unsigned rounding = 0x7FFFu + ((u >> 16) & 1u);
    return (unsigned short)((u + rounding) >> 16);
}
__device__ __forceinline__ float bf2f(unsigned short b) {
    return __uint_as_float(((unsigned)b) << 16);
}

constexpr int NB_HIST = (E_N + 255) / 256;   // 3125
constexpr int NB_PROJ = (U_N + 63) / 64;     // 782

// ---------------------------------------------------------------------------
// proj body: P[row0..row0+64][128] = X @ W (64x128), bf16 output
// ---------------------------------------------------------------------------
__device__ __forceinline__ void proj_body(const float* __restrict__ X,
                                          const float* __restrict__ W,
                                          unsigned short* __restrict__ P,
                                          int N, int row0,
                                          float* sW, float* sX)
{
    const int tid = threadIdx.x;

    for (int i = tid * 4; i < 64 * 128; i += 1024)
        *(float4*)&sW[i] = *(const float4*)&W[i];
    for (int i = tid * 4; i < 64 * 64; i += 1024) {
        int r = i >> 6, c = i & 63;
        int gr = row0 + r;
        float4 val = (gr < N) ? *(const float4*)&X[(size_t)gr * 64 + c]
                              : make_float4(0.f, 0.f, 0.f, 0.f);
        *(float4*)&sX[i] = val;
    }
    __syncthreads();

    const int cg = tid & 31, rg = tid >> 5;
    const int c0 = cg * 4, r0 = rg * 8;
    float acc[8][4];
#pragma unroll
    for (int i = 0; i < 8; ++i)
#pragma unroll
        for (int j = 0; j < 4; ++j) acc[i][j] = 0.f;

#pragma unroll 4
    for (int k = 0; k < 64; ++k) {
        float4 w = *(const float4*)&sW[k * 128 + c0];
#pragma unroll
        for (int i = 0; i < 8; ++i) {
            float x = sX[(r0 + i) * 64 + k];
            acc[i][0] += x * w.x; acc[i][1] += x * w.y;
            acc[i][2] += x * w.z; acc[i][3] += x * w.w;
        }
    }
#pragma unroll
    for (int i = 0; i < 8; ++i) {
        int gr = row0 + r0 + i;
        if (gr < N) {
            ushort4 o;
            o.x = f2bf(acc[i][0]); o.y = f2bf(acc[i][1]);
            o.z = f2bf(acc[i][2]); o.w = f2bf(acc[i][3]);
            *(ushort4*)&P[(size_t)gr * 128 + c0] = o;
        }
    }
}

// ---------------------------------------------------------------------------
// prep kernel: [0,NB_HIST) histogram; then projU, projV (bf16); last block
// packs W2f (layer-2 B-frags) and Wef (layer-1 A-frags, K padded to 32).
// ---------------------------------------------------------------------------
__global__ __launch_bounds__(256) void prep_kernel(
    const int* __restrict__ idx_u, int* __restrict__ counts,
    const float* __restrict__ u, const float* __restrict__ v,
    const float* __restrict__ gw1, const float* __restrict__ gw2,
    unsigned short* __restrict__ Up, unsigned short* __restrict__ Vp,
    unsigned short* __restrict__ W2f, unsigned short* __restrict__ Wef)
{
    __shared__ float sW[64 * 128];
    __shared__ float sX[64 * 64];
    int b = blockIdx.x;

    if (b < NB_HIST) {
        int e = b * 256 + threadIdx.x;
        if (e < E_N) atomicAdd(&counts[idx_u[e]], 1);
        return;
    }
    b -= NB_HIST;
    if (b < NB_PROJ) {
        proj_body(u, gw1, Up, U_N, b * 64, sW, sX);
        return;
    }
    b -= NB_PROJ;
    if (b < NB_PROJ) {
        proj_body(v, gw1 + 64 * 128, Vp, V_N, b * 64, sW, sX);
        return;
    }
    // ---- weight packing ----
    const int tid = threadIdx.x;
    for (int t = tid; t < 4 * 4 * 64 * 8; t += 256) {   // W2f: 8192
        int j    = t & 7;
        int lane = (t >> 3) & 63;
        int nt   = (t >> 9) & 3;
        int ks   = t >> 11;
        int n = nt * 16 + (lane & 15);
        int k = ks * 32 + (lane >> 4) * 8 + j;
        W2f[t] = f2bf(gw2[k * 64 + n]);
    }
    const float* gw1e = gw1 + 128 * 128;   // 16 x 128
    for (int t = tid; t < 8 * 64 * 8; t += 256) {       // Wef: 4096
        int j    = t & 7;
        int lane = (t >> 3) & 63;
        int ct   = t >> 9;
        int c = ct * 16 + (lane & 15);
        int k = (lane >> 4) * 8 + j;
        Wef[t] = (k < 16) ? f2bf(gw1e[k * 128 + c]) : (unsigned short)0;
    }
}

// ---------------------------------------------------------------------------
// single block, 1024 threads: in-place exclusive scan of counts[0..U_N)
// ---------------------------------------------------------------------------
__global__ __launch_bounds__(1024) void scan_kernel(int* __restrict__ counts)
{
    __shared__ int sPart[1024];
    const int tid = threadIdx.x;
    constexpr int CH = 49;          // 1024*49 = 50176 >= 50000
    const int base = tid * CH;

    int sum = 0;
#pragma unroll
    for (int k = 0; k < CH; ++k) {
        int i = base + k;
        if (i < U_N) sum += counts[i];
    }
    sPart[tid] = sum;
    __syncthreads();
    for (int off = 1; off < 1024; off <<= 1) {
        int val = (tid >= off) ? sPart[tid - off] : 0;
        __syncthreads();
        sPart[tid] += val;
        __syncthreads();
    }
    int run = sPart[tid] - sum;     // exclusive prefix for this chunk
    for (int k = 0; k < CH; ++k) {
        int i = base + k;
        if (i < U_N) { int c = counts[i]; counts[i] = run; run += c; }
    }
}

// ---------------------------------------------------------------------------
// permute+gather: scatter edges into sorted order, pre-gathering everything
// the edge kernel needs: iuv packed indices + ev row as bf16.
// ---------------------------------------------------------------------------
__global__ __launch_bounds__(256) void permute_kernel(
    const int* __restrict__ idx_u, const int* __restrict__ idx_v,
    const float* __restrict__ ev, int* __restrict__ cursor,
    unsigned int* __restrict__ iuv_s, unsigned short* __restrict__ evs)
{
    int e = blockIdx.x * 256 + threadIdx.x;
    if (e >= E_N) return;
    int iu = idx_u[e];
    int iv = idx_v[e];
    int pos = atomicAdd(&cursor[iu], 1);
    iuv_s[pos] = (unsigned)iu | ((unsigned)iv << 16);

    // ev row fp32->bf16, coalesced read, scattered 32B write
    const float* src = &ev[(size_t)e * 16];
    unsigned short* dst = &evs[(size_t)pos * 16];
#pragma unroll
    for (int q = 0; q < 4; ++q) {
        float4 a = *(const float4*)&src[q * 4];
        ushort4 o;
        o.x = f2bf(a.x); o.y = f2bf(a.y); o.z = f2bf(a.z); o.w = f2bf(a.w);
        *(ushort4*)&dst[q * 4] = o;
    }
}

// ---------------------------------------------------------------------------
// edge kernel over SORTED pre-gathered edges: 64 edges/block, 4 waves.
// All loads coalesced except Up (run-local, L1-hot) and Vp (LLC) gathers,
// which are register-prefetched 16-deep before the MFMA work.
// layer 1 (MFMA, transposed): D[c][e]; layer 2 (MFMA): h2 = relu(h1@W2+b2);
// wave-local segmented reduction -> few atomics.
// ---------------------------------------------------------------------------
__global__ __launch_bounds__(256, 5) void edge_kernel(
    const unsigned short* __restrict__ Up,   // 50000 x 128 bf16
    const unsigned short* __restrict__ Vp,   // 50000 x 128 bf16
    const unsigned short* __restrict__ evs,  // E x 16 bf16, sorted
    const unsigned int* __restrict__ iuv_s,  // E packed (iu | iv<<16), sorted
    const unsigned short* __restrict__ Wef,  // layer-1 A frags (We^T, K=32 pad)
    const float* __restrict__ gb1,
    const unsigned short* __restrict__ W2f,  // layer-2 B frags
    const float* __restrict__ gb2,
    float* __restrict__ agg)
{
    __shared__ unsigned short sH1[64 * 136];  // 17408 B; aliased as sH2 f32 [64][68]
    __shared__ int sIu[64];

    const int tid = threadIdx.x;
    const int e0 = blockIdx.x * 64;
    const int wid = tid >> 6, lane = tid & 63;
    const int lo = lane & 15, hi = lane >> 4;
    const int g = e0 + wid * 16 + lo;         // this lane's (sorted) edge

    const unsigned iuv = iuv_s[g];
    const int iu = (int)(iuv & 0xFFFFu);
    const int iv = (int)(iuv >> 16);
    if (hi == 0) sIu[wid * 16 + lo] = iu;     // wave-local write

    // ---- register-prefetch the gathers (16 independent 8B loads) ----
    ushort4 upv[8], vpv[8];
#pragma unroll
    for (int ct = 0; ct < 8; ++ct) {
        upv[ct] = *(const ushort4*)&Up[(size_t)iu * 128 + ct * 16 + hi * 4];
        vpv[ct] = *(const ushort4*)&Vp[(size_t)iv * 128 + ct * 16 + hi * 4];
    }

    // ---- layer 1 MFMA: B-frag = evs row (coalesced); A = Wef (L1-hot) ----
    bf16x8 bfrag;
    if (hi < 2) {
        bfrag = *(const bf16x8*)&evs[(size_t)g * 16 + hi * 8];
    } else {
        bfrag = (bf16x8)(short)0;             // K-pad 16->32
    }

    f32x4 acc[8];
#pragma unroll
    for (int ct = 0; ct < 8; ++ct) {
#pragma unroll
        for (int r = 0; r < 4; ++r) acc[ct][r] = 0.f;
        bf16x8 a = *(const bf16x8*)&Wef[(size_t)((ct * 64 + lane) * 8)];
        acc[ct] = __builtin_amdgcn_mfma_f32_16x16x32_bf16(a, bfrag, acc[ct], 0, 0, 0);
    }

    // epilogue: h1 = relu(acc + b1 + Up[iu] + Vp[iv]) -> bf16 LDS (wave-local)
    const int e_loc = wid * 16 + lo;
#pragma unroll
    for (int ct = 0; ct < 8; ++ct) {
        int c0 = ct * 16 + hi * 4;
        float4 b1 = *(const float4*)&gb1[c0];
        ushort4 uv = upv[ct], vv = vpv[ct];
        ushort4 h;
        h.x = f2bf(relu(acc[ct][0] + b1.x + bf2f(uv.x) + bf2f(vv.x)));
        h.y = f2bf(relu(acc[ct][1] + b1.y + bf2f(uv.y) + bf2f(vv.y)));
        h.z = f2bf(relu(acc[ct][2] + b1.z + bf2f(uv.z) + bf2f(vv.z)));
        h.w = f2bf(relu(acc[ct][3] + b1.w + bf2f(uv.w) + bf2f(vv.w)));
        *(ushort4*)&sH1[e_loc * 136 + c0] = h;
    }
    // intra-wave ushort write->read on same array: compiler-ordered, no barrier

    // ---- layer 2 via MFMA: wave reads its OWN 16 rows of sH1 ----
    f32x4 accm[4];
#pragma unroll
    for (int nt = 0; nt < 4; ++nt)
#pragma unroll
        for (int r = 0; r < 4; ++r) accm[nt][r] = 0.f;

#pragma unroll
    for (int ks = 0; ks < 4; ++ks) {
        bf16x8 a = *(const bf16x8*)&sH1[(wid * 16 + lo) * 136 + ks * 32 + hi * 8];
#pragma unroll
        for (int nt = 0; nt < 4; ++nt) {
            bf16x8 b = *(const bf16x8*)&W2f[(size_t)(((ks * 4 + nt) * 64 + lane) * 8)];
            accm[nt] = __builtin_amdgcn_mfma_f32_16x16x32_bf16(a, b, accm[nt], 0, 0, 0);
        }
    }
    __syncthreads();   // alias (ushort->float) boundary: all sH1 reads done

    float* sH2 = (float*)sH1;   // [64][68] fp32; wave-local byte range coincides
#pragma unroll
    for (int nt = 0; nt < 4; ++nt) {
        int col = nt * 16 + lo;
        float b2v = gb2[col];
        int erow = wid * 16 + hi * 4;
#pragma unroll
        for (int r = 0; r < 4; ++r)
            sH2[(erow + r) * 68 + col] = relu(accm[nt][r] + b2v);
    }
    // reduction reads own wave's rows (float->float, intra-wave): no barrier

    // ---- segmented reduction over sorted iu: thread = (col, own wave) ----
    {
        const int c = tid & 63;       // output column
        const int eq0 = wid * 16;     // this wave's 16 edges
        int   iu_cur = sIu[eq0];
        float running = 0.f;
#pragma unroll
        for (int k = 0; k < 16; ++k) {
            int e = eq0 + k;
            int iu2 = sIu[e];
            if (iu2 != iu_cur) {
                atomicAdd(&agg[(size_t)iu_cur * 64 + c], running);
                running = 0.f;
                iu_cur = iu2;
            }
            running += sH2[e * 68 + c];
        }
        atomicAdd(&agg[(size_t)iu_cur * 64 + c], running);
    }
}

// ---------------------------------------------------------------------------
// node kernel: out = relu(relu([u, agg] @ fw1 + fb1) @ fw2 + fb2)
// ---------------------------------------------------------------------------
__global__ __launch_bounds__(256) void node_kernel(
    const float* __restrict__ u, const float* __restrict__ agg,
    const float* __restrict__ fw1, const float* __restrict__ fb1,
    const float* __restrict__ fw2, const float* __restrict__ fb2,
    float* __restrict__ out, int N)
{
    __shared__ float sX[64 * 128];  // 32 KB
    __shared__ float sY[64 * 132];  // 33 KB
    const int tid = threadIdx.x;
    const int row0 = blockIdx.x * 64;

    for (int i = tid * 4; i < 64 * 64; i += 1024) {
        int r = i >> 6, c = i & 63;
        int gr = row0 + r;
        float4 uu = (gr < N) ? *(const float4*)&u[(size_t)gr * 64 + c]
                             : make_float4(0.f, 0.f, 0.f, 0.f);
        float4 aa = (gr < N) ? *(const float4*)&agg[(size_t)gr * 64 + c]
                             : make_float4(0.f, 0.f, 0.f, 0.f);
        *(float4*)&sX[r * 128 + c] = uu;
        *(float4*)&sX[r * 128 + 64 + c] = aa;
    }
    __syncthreads();

    {
        const int cg = tid & 31, rg = tid >> 5;
        const int c0 = cg * 4, r0 = rg * 8;
        const float4 b = *(const float4*)&fb1[c0];
        float acc[8][4];
#pragma unroll
        for (int i = 0; i < 8; ++i) {
            acc[i][0] = b.x; acc[i][1] = b.y; acc[i][2] = b.z; acc[i][3] = b.w;
        }
#pragma unroll 4
        for (int k = 0; k < 128; ++k) {
            float4 w = *(const float4*)&fw1[k * 128 + c0];
#pragma unroll
            for (int i = 0; i < 8; ++i) {
                float x = sX[(r0 + i) * 128 + k];
                acc[i][0] += x * w.x; acc[i][1] += x * w.y;
                acc[i][2] += x * w.z; acc[i][3] += x * w.w;
            }
        }
#pragma unroll
        for (int i = 0; i < 8; ++i) {
            float4 h = make_float4(relu(acc[i][0]), relu(acc[i][1]),
                                   relu(acc[i][2]), relu(acc[i][3]));
            *(float4*)&sY[(r0 + i) * 132 + c0] = h;
        }
    }
    __syncthreads();

    {
        const int cg = tid & 15, rg = tid >> 4;
        const int c0 = cg * 4;
        const float4 b = *(const float4*)&fb2[c0];
        float acc[4][4];
#pragma unroll
        for (int i = 0; i < 4; ++i) {
            acc[i][0] = b.x; acc[i][1] = b.y; acc[i][2] = b.z; acc[i][3] = b.w;
        }
#pragma unroll 4
        for (int k = 0; k < 128; ++k) {
            float4 w = *(const float4*)&fw2[k * 64 + c0];
#pragma unroll
            for (int i = 0; i < 4; ++i) {
                float yv = sY[(rg * 4 + i) * 132 + k];
                acc[i][0] += yv * w.x; acc[i][1] += yv * w.y;
                acc[i][2] += yv * w.z; acc[i][3] += yv * w.w;
            }
        }
#pragma unroll
        for (int i = 0; i < 4; ++i) {
            int gr = row0 + rg * 4 + i;
            if (gr < N) {
                float4 o = make_float4(relu(acc[i][0]), relu(acc[i][1]),
                                       relu(acc[i][2]), relu(acc[i][3]));
                *(float4*)&out[(size_t)gr * 64 + c0] = o;
            }
        }
    }
}

// ---------------------------------------------------------------------------
extern "C" void kernel_launch(void* const* d_in, const int* in_sizes, int n_in,
                              void* d_out, int out_size, void* d_ws, size_t ws_size,
                              hipStream_t stream)
{
    const float* u   = (const float*)d_in[0];
    const float* v   = (const float*)d_in[1];
    const float* ev  = (const float*)d_in[2];
    const int*   eiv = (const int*)d_in[3];
    const int*   eiu = (const int*)d_in[4];
    const float* gw1 = (const float*)d_in[5];   // 144 x 128
    const float* gb1 = (const float*)d_in[6];   // 128
    const float* gw2 = (const float*)d_in[7];   // 128 x 64
    const float* gb2 = (const float*)d_in[8];   // 64
    const float* fw1 = (const float*)d_in[9];   // 128 x 128
    const float* fb1 = (const float*)d_in[10];  // 128
    const float* fw2 = (const float*)d_in[11];  // 128 x 64
    const float* fb2 = (const float*)d_in[12];  // 64
    float* out = (float*)d_out;

    // workspace layout (agg and counts adjacent -> single memset); ~67.4 MB
    unsigned short* Up     = (unsigned short*)d_ws;                 // 50000x128 bf16
    unsigned short* Vp     = Up + (size_t)U_N * 128;                // 50000x128 bf16
    unsigned short* evs    = Vp + (size_t)V_N * 128;                // E x 16 bf16
    float*          agg    = (float*)(evs + (size_t)E_N * 16);      // 50000x64 f32
    int*            counts = (int*)(agg + (size_t)U_N * 64);        // 50000 (= cursor)
    unsigned int*   iuv_s  = (unsigned int*)(counts + U_N);         // 800000
    unsigned short* W2f    = (unsigned short*)(iuv_s + E_N);        // 8192 bf16
    unsigned short* Wef    = W2f + 8192;                            // 4096 bf16

    // one memset covers agg (zero init) + counts (hist init)
    hipMemsetAsync(agg, 0, ((size_t)U_N * 64 + U_N) * sizeof(float), stream);

    dim3 blk(256);
    prep_kernel<<<dim3(NB_HIST + 2 * NB_PROJ + 1), blk, 0, stream>>>(
        eiu, counts, u, v, gw1, gw2, Up, Vp, W2f, Wef);
    scan_kernel<<<dim3(1), dim3(1024), 0, stream>>>(counts);
    permute_kernel<<<dim3(NB_HIST), blk, 0, stream>>>(
        eiu, eiv, ev, counts, iuv_s, evs);

    edge_kernel<<<dim3(E_N / 64), blk, 0, stream>>>(
        Up, Vp, evs, iuv_s, Wef, gb1, W2f, gb2, agg);
    node_kernel<<<dim3((U_N + 63) / 64), blk, 0, stream>>>(
        u, agg, fw1, fb1, fw2, fb2, out, U_N);
}